// Round 11
// baseline (224.083 us; speedup 1.0000x reference)
//
#include <hip/hip_runtime.h>
#include <math.h>

typedef unsigned short u16;
typedef __attribute__((ext_vector_type(8))) short short8;    // 8 bf16 (4 VGPR)
typedef __attribute__((ext_vector_type(4))) float floatx4;
typedef __attribute__((ext_vector_type(4))) u16 v4u16;
typedef __attribute__((ext_vector_type(8))) u16 v8u16;

#define B_   16
#define C_   512
#define NSP  1024
#define EPSV 1e-5f
#define QSCALE 0.18033688011117f   // 0.125 * log2(e) — softmax in base 2

__device__ __forceinline__ u16 f2bf(float f) {
  union { float f; unsigned u; } v; v.f = f;
  unsigned r = v.u + 0x7FFFu + ((v.u >> 16) & 1u);   // RNE
  return (u16)(r >> 16);
}

__device__ __forceinline__ void gld16(const u16* g, u16* l) {
  __builtin_amdgcn_global_load_lds(
      (const __attribute__((address_space(1))) void*)g,
      (__attribute__((address_space(3))) void*)l, 16, 0, 0);
}

// inline-asm ds_read_b128 (R5, validated): invisible to alias analysis, so
// not ordered against outstanding global_load_lds. "=&v" early-clobber.
// Caller guarantees the buffer landed (explicit vmcnt/barrier protocol) and
// follows the group with s_waitcnt lgkmcnt(0) + sched_barrier(0) (rule #18).
__device__ __forceinline__ short8 lds_read_b128(const u16* p) {
  short8 r;
  asm volatile("ds_read_b128 %0, %1"
               : "=&v"(r)
               : "v"((const __attribute__((address_space(3))) u16*)p));
  return r;
}

// inline-asm global->VGPR 16B load. "memory" clobber keeps builtin
// global_load_lds ops from crossing (deterministic VMEM issue order).
__device__ __forceinline__ short8 gload_b128(const u16* p) {
  short8 r;
  asm volatile("global_load_dwordx4 %0, %1, off"
               : "=&v"(r)
               : "v"((const __attribute__((address_space(1))) u16*)p)
               : "memory");
  return r;
}

template <int N> __device__ __forceinline__ void wait_vm() {
  asm volatile("s_waitcnt vmcnt(%0)" :: "n"(N) : "memory");
}
template <int N> __device__ __forceinline__ void wait_vm_lgkm() {
  asm volatile("s_waitcnt vmcnt(%0) lgkmcnt(0)" :: "n"(N) : "memory");
}

// pack hi16(a)|hi16(b)<<16 : bf16 truncation pack, 1 instr
__device__ __forceinline__ unsigned pk_bf(float a, float b) {
  return __builtin_amdgcn_perm(__float_as_uint(b), __float_as_uint(a), 0x07060302u);
}

// ------- GroupNorm pass 1 + fp32->bf16 weight cvt, one launch (2048 blk) ---
__global__ __launch_bounds__(256) void gn_stats_cvt(
    const float* __restrict__ x, float* __restrict__ stats,
    const float* __restrict__ qa, u16* __restrict__ oa,     // 1536*512
    const float* __restrict__ pa, u16* __restrict__ ob)     // 512*512
{
  int blk = blockIdx.x;
  if (blk >= 1024) {               // ---- cvt path ----
    int cb = blk - 1024;
    const float* in; u16* out; int i;
    if (cb < 768) { in = qa; out = oa; i = (cb * 256 + threadIdx.x) * 4; }
    else          { in = pa; out = ob; i = ((cb - 768) * 256 + threadIdx.x) * 4; }
    float4 v = *(const float4*)(in + i);
    v4u16 o = { f2bf(v.x), f2bf(v.y), f2bf(v.z), f2bf(v.w) };
    *(v4u16*)(out + i) = o;
    return;
  }
  // ---- gn_stats path ----
  int bg = blk >> 3, ck = blk & 7;
  const float4* xp = (const float4*)(x + (((size_t)bg * 64 + ck * 8) * NSP));
  float s = 0.f, ss = 0.f;
#pragma unroll
  for (int it = 0; it < 8; ++it) {
    float4 v = xp[it * 256 + threadIdx.x];
    s  += v.x + v.y + v.z + v.w;
    ss += v.x * v.x + v.y * v.y + v.z * v.z + v.w * v.w;
  }
  for (int off = 32; off > 0; off >>= 1) {
    s  += __shfl_down(s, off);
    ss += __shfl_down(ss, off);
  }
  __shared__ float rs[4], rss[4];
  int lane = threadIdx.x & 63, wv = threadIdx.x >> 6;
  if (lane == 0) { rs[wv] = s; rss[wv] = ss; }
  __syncthreads();
  if (threadIdx.x == 0) {
    float S  = rs[0] + rs[1] + rs[2] + rs[3];
    float SS = rss[0] + rss[1] + rss[2] + rss[3];
    atomicAdd(&stats[bg * 2], S);
    atomicAdd(&stats[bg * 2 + 1], SS);
  }
}

// ------------- GroupNorm pass 2: normalize + transpose to [b][n][c] -------
__global__ __launch_bounds__(256) void gn_apply(
    const float* __restrict__ x, const float* __restrict__ stats,
    const float* __restrict__ gw, const float* __restrict__ gb,
    u16* __restrict__ xn)
{
  int blk = blockIdx.x;            // bg*16 + nt
  int bg = blk >> 4, nt = blk & 15;
  int b = bg >> 3, g = bg & 7;
  float S = stats[bg * 2], SS = stats[bg * 2 + 1];
  float mu  = S * (1.f / 65536.f);
  float var = SS * (1.f / 65536.f) - mu * mu;
  float inv = rsqrtf(var + EPSV);
  __shared__ float T[64][65];
  const float* xb = x + (size_t)bg * 64 * NSP;
  int t = threadIdx.x;
#pragma unroll
  for (int it = 0; it < 4; ++it) {
    int task = it * 256 + t;
    int cc = task >> 4, ns = task & 15;
    float4 v = *(const float4*)(xb + (size_t)cc * NSP + nt * 64 + ns * 4);
    T[cc][ns * 4 + 0] = v.x; T[cc][ns * 4 + 1] = v.y;
    T[cc][ns * 4 + 2] = v.z; T[cc][ns * 4 + 3] = v.w;
  }
  __syncthreads();
#pragma unroll
  for (int it = 0; it < 2; ++it) {
    int task = it * 256 + t;
    int n = task >> 3, cs = task & 7;
    v8u16 o;
#pragma unroll
    for (int u = 0; u < 8; ++u) {
      int cg = g * 64 + cs * 8 + u;
      float val = (T[cs * 8 + u][n] - mu) * inv * gw[cg] + gb[cg];
      o[u] = f2bf(val);
    }
    *(v8u16*)(xn + ((size_t)b * NSP + nt * 64 + n) * C_ + g * 64 + cs * 8) = o;
  }
}

// ---- bf16 MFMA GEMM v10c: A direct global->reg, B-only LDS staging ----
// R10 NaN root-cause (third audit): __launch_bounds__(256,4) capped VGPR at
// 128 < the ~140 demand -> compiler emitted SCRATCH SPILLS, and scratch
// ops increment vmcnt -> the counted-vmcnt protocol's "leave 6 outstanding"
// could leave needed B/A loads un-retired -> ds_read of unwritten LDS ->
// NaN. R8's validated gemm (96 VGPR, no cap) never spilled. Fix: plain
// __launch_bounds__(256) — demand ~140 < 256, zero spills, pure vmcnt
// stream. Occupancy ~3 blocks/CU (VGPR-limited); the win is instruction
// traffic: per body ds_read 8->4, gld16 4->2, no A LDS round-trip.
// Protocol (6 VMEM/body = 2 gld16-B + 4 asm-A, deterministic order via
// "memory" clobber):
//   body k: [vmcnt(4) if k==0] barrier; stageB(k+2); afload(k+1);
//           ds_read B(k); vmcnt(6)+lgkm(0); MFMA af(k).
//   vmcnt(6) retires all of body k-1's 6 ops => af(k) + B(k+1) landed;
//   barrier-after-own-wait publishes B cross-wave. Tails vmcnt(4)/(0).
// MODE 0 (qkv): m<1024 -> out_qk[b][n][m] (Q scaled); m>=1024 -> out_v
//   k-permuted (k=(j&0x23)|((j&0x0C)<<1)|((j&0x10)>>2)) for attn b128 frags.
// MODE 1 (proj): out_f[b][m][n] fp32 = acc + bias + resid.
template <int MODE>
__global__ __launch_bounds__(256) void gemm_mfma(
    const u16* __restrict__ W, const u16* __restrict__ X,
    const float* __restrict__ bias, const float* __restrict__ resid,
    u16* __restrict__ out_qk, u16* __restrict__ out_v,
    float* __restrict__ out_f)
{
  __shared__ u16 smem[12288];      // 3 x 8KB B-stage bufs; epilogue overlays
  int id = blockIdx.x;
  int yb = id >> 7, rr = id & 127;
  int b = rr >> 3, xb_ = rr & 7;
  int m0 = yb * 128, n0 = xb_ * 128;
  int t = threadIdx.x, lane = t & 63, w = t >> 6;
  int c = lane & 15, q = lane >> 4;
  int wm = w >> 1, wn = w & 1;
  const u16* Xb = X + (size_t)b * NSP * C_;

  floatx4 acc[4][4];
#pragma unroll
  for (int mi = 0; mi < 4; ++mi)
#pragma unroll
    for (int ni = 0; ni < 4; ++ni) acc[mi][ni] = (floatx4){0.f, 0.f, 0.f, 0.f};

  auto stageB = [&](int buf, int k0) {
    u16* Bsb = smem + buf * 4096;
#pragma unroll
    for (int it = 0; it < 2; ++it) {
      int task = it * 256 + t;
      int nr = task >> 2;
      int gk = (task & 3) ^ ((nr >> 1) & 3);
      gld16(Xb + (size_t)(n0 + nr) * C_ + k0 + gk * 8, Bsb + task * 8);
    }
  };

  // per-lane W base pointers for the 4 A-frags (advance by k*32 u16)
  const u16* wl[4];
#pragma unroll
  for (int mi = 0; mi < 4; ++mi)
    wl[mi] = W + (size_t)(m0 + wm * 64 + mi * 16 + c) * C_ + q * 8;

  short8 afA[4], afB[4];

  stageB(0, 0);
  stageB(1, 32);
#pragma unroll
  for (int mi = 0; mi < 4; ++mi) afA[mi] = gload_b128(wl[mi]);   // af(0)

#define GEMM_BODY(KI, AFC, AFN, BUFC, DOSTAGE, DOAF, PREW, MFW)            \
  {                                                                        \
    if (PREW) wait_vm<4>();  /* body0: BOTH prologue B stages landed */    \
    __builtin_amdgcn_s_barrier();                                          \
    if (DOSTAGE) stageB(((BUFC) + 2) % 3, ((KI) + 2) * 32);                \
    if (DOAF) {                                                            \
      _Pragma("unroll")                                                    \
      for (int mi = 0; mi < 4; ++mi)                                       \
        AFN[mi] = gload_b128(wl[mi] + ((KI) + 1) * 32);                    \
    }                                                                      \
    __builtin_amdgcn_sched_barrier(0);                                     \
    const u16* Bs = smem + (BUFC) * 4096;                                  \
    short8 bfr[4];                                                         \
    _Pragma("unroll")                                                      \
    for (int ni = 0; ni < 4; ++ni) {                                       \
      int n = wn * 64 + ni * 16 + c;                                       \
      bfr[ni] = lds_read_b128(Bs + n * 32 + ((q ^ ((n >> 1) & 3)) << 3));  \
    }                                                                      \
    wait_vm_lgkm<MFW>();                                                   \
    __builtin_amdgcn_sched_barrier(0);                                     \
    _Pragma("unroll")                                                      \
    for (int mi = 0; mi < 4; ++mi) {                                       \
      _Pragma("unroll")                                                    \
      for (int ni = 0; ni < 4; ++ni)                                       \
        acc[mi][ni] = __builtin_amdgcn_mfma_f32_16x16x32_bf16(             \
            AFC[mi], bfr[ni], acc[mi][ni], 0, 0, 0);                       \
    }                                                                      \
  }

  GEMM_BODY(0, afA, afB, 0, true, true, true, 6);
  GEMM_BODY(1, afB, afA, 1, true, true, false, 6);
#pragma unroll
  for (int kk = 1; kk <= 6; ++kk) {
    GEMM_BODY(2 * kk,     afA, afB, (2 * kk) % 3,     true, true, false, 6);
    GEMM_BODY(2 * kk + 1, afB, afA, (2 * kk + 1) % 3, true, true, false, 6);
  }
  GEMM_BODY(14, afA, afB, 2, false, true,  false, 4);
  GEMM_BODY(15, afB, afA, 0, false, false, false, 0);
#undef GEMM_BODY
  __syncthreads();                 // all waves done before epilogue overlay

  if (MODE == 0) {
    if (m0 < 1024) {       // Q/K region: transpose to [n][m], two m-halves
      float sc = (m0 < 512) ? QSCALE : 1.0f;
      u16* Cl = smem;      // [128 n][72 m-half stride] = 18KB
#pragma unroll
      for (int mh = 0; mh < 2; ++mh) {
        if (wm == mh) {
#pragma unroll
          for (int mi = 0; mi < 4; ++mi) {
            floatx4 bi = *(const floatx4*)(bias + m0 + mh * 64 + mi * 16 + q * 4);
#pragma unroll
            for (int ni = 0; ni < 4; ++ni) {
              int n = wn * 64 + ni * 16 + c;
              int ml = mi * 16 + q * 4;
              v4u16 pk;
#pragma unroll
              for (int r = 0; r < 4; ++r) pk[r] = f2bf((acc[mi][ni][r] + bi[r]) * sc);
              *(v4u16*)(Cl + n * 72 + ml) = pk;
            }
          }
        }
        __syncthreads();
#pragma unroll
        for (int it = 0; it < 4; ++it) {
          int task = it * 256 + t;
          int n = task >> 3, seg = task & 7;
          v8u16 v = *(const v8u16*)(Cl + n * 72 + seg * 8);
          *(v8u16*)(out_qk + ((size_t)b * NSP + n0 + n) * 1024 +
                    m0 + mh * 64 + seg * 8) = v;
        }
        __syncthreads();
      }
    } else {               // V region: [m][n'] k-permuted, two m-halves
      u16* Cl = smem;      // [64 m][136 n-stride] = 17KB
#pragma unroll
      for (int mh = 0; mh < 2; ++mh) {
        if (wm == mh) {
#pragma unroll
          for (int mi = 0; mi < 4; ++mi) {
            floatx4 bi = *(const floatx4*)(bias + m0 + mh * 64 + mi * 16 + q * 4);
#pragma unroll
            for (int ni = 0; ni < 4; ++ni) {
              int n = wn * 64 + ni * 16 + c;
              int ml = mi * 16 + q * 4;
#pragma unroll
              for (int r = 0; r < 4; ++r)
                Cl[(ml + r) * 136 + n] = f2bf(acc[mi][ni][r] + bi[r]);
            }
          }
        }
        __syncthreads();
        // k-permutation: k0 = ((s&4)<<3)|((s&1)<<4)|((s&2)<<1), s = seg&7
#pragma unroll
        for (int it = 0; it < 4; ++it) {
          int task = it * 256 + t;
          int m = task >> 4, seg = task & 15;
          int g64 = seg >> 3, s = seg & 7;
          int k0 = ((s & 4) << 3) | ((s & 1) << 4) | ((s & 2) << 1);
          v8u16 v = *(const v8u16*)(Cl + m * 136 + seg * 8);
          v4u16 lo = { v[0], v[1], v[2], v[3] };
          v4u16 hi = { v[4], v[5], v[6], v[7] };
          size_t base = ((size_t)b * C_ + m0 - 1024 + mh * 64 + m) * NSP +
                        n0 + g64 * 64;
          *(v4u16*)(out_v + base + k0) = lo;
          *(v4u16*)(out_v + base + k0 + 8) = hi;
        }
        __syncthreads();
      }
    }
  } else {                 // proj: fp32 [m][n] + bias + residual
#pragma unroll
    for (int mi = 0; mi < 4; ++mi) {
      floatx4 bi = *(const floatx4*)(bias + m0 + wm * 64 + mi * 16 + q * 4);
#pragma unroll
      for (int ni = 0; ni < 4; ++ni) {
        int n = n0 + wn * 64 + ni * 16 + c;
        int m = m0 + wm * 64 + mi * 16 + q * 4;
#pragma unroll
        for (int r = 0; r < 4; ++r) {
          size_t o = ((size_t)b * C_ + m + r) * NSP + n;
          out_f[o] = acc[mi][ni][r] + bi[r] + resid[o];
        }
      }
    }
  }
}

// ---- flash attention v10 (R8, validated): counted-vmcnt barriers (T4) ----
// 4 waves x 32 q-rows; jt2-interleaved QK/exp/PV; asm ds_read frags;
// denominator via mfma(ones,P); V k-permuted; s_setprio around PV.
// Loop protocol: issue prefetch -> vmcnt(4) (previous iter's loads only;
// this iter's 4 stay in flight across the barrier) -> compute -> raw
// s_barrier. Tail j0=15: vmcnt(0). VGPR ~60 < 128 -> no spills, counted
// stream pure.
__global__ __launch_bounds__(256, 4) void attn_mfma(
    const u16* __restrict__ qk, const u16* __restrict__ vbuf,
    u16* __restrict__ att)
{
  __shared__ u16 __align__(16) smem[16384];   // 32 KB
  int id = blockIdx.x;
  int hb = id & 127;
  int i0 = id >> 7;
  int h = hb >> 4, b = hb & 15;
  int t = threadIdx.x, lane = t & 63, w = t >> 6;
  int c = lane & 15, q = lane >> 4;
  const u16* qbase = qk + (size_t)b * NSP * 1024;
  const u16* vbase = vbuf + (size_t)(b * C_ + h * 64) * NSP;

  // stage Q(128x64) -> [0..8192); K0 -> [8192..12288); V0 -> [12288..16384)
#pragma unroll
  for (int it = 0; it < 4; ++it) {
    int task = it * 256 + t;
    int r = task >> 3, seg = task & 7, ds = (seg ^ (r & 7)) * 8;
    gld16(qbase + (size_t)(i0 * 128 + r) * 1024 + h * 64 + ds, smem + task * 8);
  }
#pragma unroll
  for (int it = 0; it < 2; ++it) {
    int task = it * 256 + t;
    int r = task >> 3, seg = task & 7, ds = (seg ^ (r & 7)) * 8;
    gld16(qbase + (size_t)r * 1024 + 512 + h * 64 + ds, smem + 8192 + task * 8);
    gld16(vbase + (size_t)r * NSP + ds, smem + 12288 + task * 8);
  }
  __syncthreads();

  short8 qa[2][2];                 // rows w*32 + nf*16 + c
#pragma unroll
  for (int nf = 0; nf < 2; ++nf) {
    int row = w * 32 + nf * 16 + c;
#pragma unroll
    for (int ch = 0; ch < 2; ++ch)
      qa[nf][ch] = *(const short8*)(smem + row * 64 + (((q + 4 * ch) ^ (c & 7)) << 3));
  }
  __syncthreads();                 // all waves done reading Q before overlay

  short8 onesf;                    // all-ones bf16 A-operand (1.0 = 0x3F80)
#pragma unroll
  for (int u = 0; u < 8; ++u) onesf[u] = (short)0x3F80;

  floatx4 Oacc[4][2];              // [dt][nf]
  floatx4 OaccT[2];                // ones-MFMA column sums -> denominator
#pragma unroll
  for (int dt = 0; dt < 4; ++dt)
#pragma unroll
    for (int nf = 0; nf < 2; ++nf) Oacc[dt][nf] = (floatx4){0.f, 0.f, 0.f, 0.f};
#pragma unroll
  for (int nf = 0; nf < 2; ++nf) OaccT[nf] = (floatx4){0.f, 0.f, 0.f, 0.f};

  for (int j0 = 0; j0 < 16; ++j0) {
    int p = j0 & 1;
    u16* KS = smem + (p ? 0 : 8192);
    u16* VS = KS + 4096;
    if (j0 < 15) {                 // prefetch next K/V into the other parity
      u16* KN = smem + (p ? 8192 : 0);
      u16* VN = KN + 4096;
#pragma unroll
      for (int it = 0; it < 2; ++it) {
        int task = it * 256 + t;
        int r = task >> 3, seg = task & 7, ds = (seg ^ (r & 7)) * 8;
        gld16(qbase + (size_t)((j0 + 1) * 64 + r) * 1024 + 512 + h * 64 + ds,
              KN + task * 8);
        gld16(vbase + (size_t)r * NSP + (j0 + 1) * 64 + ds, VN + task * 8);
      }
      asm volatile("s_waitcnt vmcnt(4)" ::: "memory");
    } else {
      asm volatile("s_waitcnt vmcnt(0)" ::: "memory");   // tail: drain last
    }
    __builtin_amdgcn_sched_barrier(0);
#pragma unroll
    for (int jt2 = 0; jt2 < 2; ++jt2) {
      // --- batched asm frag reads: 4x K + 4x V, one lgkm wait ---
      short8 kb[2][2], vf[4];
#pragma unroll
      for (int jj = 0; jj < 2; ++jj) {
        int row = (jt2 * 2 + jj) * 16 + c;
        kb[jj][0] = lds_read_b128(KS + row * 64 + ((q ^ (row & 7)) << 3));
        kb[jj][1] = lds_read_b128(KS + row * 64 + (((q + 4) ^ (row & 7)) << 3));
      }
#pragma unroll
      for (int dt = 0; dt < 4; ++dt) {
        int dd = dt * 16 + c;
        vf[dt] = lds_read_b128(VS + dd * 64 + (((jt2 * 4 + q) ^ (dd & 7)) << 3));
      }
      asm volatile("s_waitcnt lgkmcnt(0)" ::: "memory");
      __builtin_amdgcn_sched_barrier(0);
      // --- QK half: S^T = K·Q^T for 32 j, base-2 exp, pack P bf16 ---
      unsigned pk2[2][2][2];
#pragma unroll
      for (int jj = 0; jj < 2; ++jj) {
#pragma unroll
        for (int nf = 0; nf < 2; ++nf) {
          floatx4 z = (floatx4){0.f, 0.f, 0.f, 0.f};
          z = __builtin_amdgcn_mfma_f32_16x16x32_bf16(kb[jj][0], qa[nf][0], z, 0, 0, 0);
          z = __builtin_amdgcn_mfma_f32_16x16x32_bf16(kb[jj][1], qa[nf][1], z, 0, 0, 0);
          float p0 = __builtin_amdgcn_exp2f(z[0]);
          float p1 = __builtin_amdgcn_exp2f(z[1]);
          float p2 = __builtin_amdgcn_exp2f(z[2]);
          float p3 = __builtin_amdgcn_exp2f(z[3]);
          pk2[jj][nf][0] = pk_bf(p0, p1);
          pk2[jj][nf][1] = pk_bf(p2, p3);
        }
      }
      short8 pf[2];
#pragma unroll
      for (int nf = 0; nf < 2; ++nf) {
        union { short8 s; unsigned d[4]; } u;
        u.d[0] = pk2[0][nf][0]; u.d[1] = pk2[0][nf][1];
        u.d[2] = pk2[1][nf][0]; u.d[3] = pk2[1][nf][1];
        pf[nf] = u.s;
      }
      // --- PV half: k-permuted V, all operands already in regs ---
      __builtin_amdgcn_s_setprio(1);
#pragma unroll
      for (int dt = 0; dt < 4; ++dt)
#pragma unroll
        for (int nf = 0; nf < 2; ++nf)
          Oacc[dt][nf] = __builtin_amdgcn_mfma_f32_16x16x32_bf16(
              vf[dt], pf[nf], Oacc[dt][nf], 0, 0, 0);
#pragma unroll
      for (int nf = 0; nf < 2; ++nf)
        OaccT[nf] = __builtin_amdgcn_mfma_f32_16x16x32_bf16(
            onesf, pf[nf], OaccT[nf], 0, 0, 0);
      __builtin_amdgcn_s_setprio(0);
    }
    __builtin_amdgcn_s_barrier();  // raw barrier: NO vmcnt drain (T4)
  }

  // ---- epilogue: denominator straight from ones-MFMA rows (all equal) ----
#pragma unroll
  for (int nf = 0; nf < 2; ++nf) {
    float rinv = 1.f / OaccT[nf][0];
    int n = i0 * 128 + w * 32 + nf * 16 + c;
#pragma unroll
    for (int dt = 0; dt < 4; ++dt) {
      v4u16 pk;
#pragma unroll
      for (int r = 0; r < 4; ++r) pk[r] = f2bf(Oacc[dt][nf][r] * rinv);
      *(v4u16*)(att + ((size_t)b * NSP + n) * C_ + h * 64 + dt * 16 + q * 4) = pk;
    }
  }
}

extern "C" void kernel_launch(void* const* d_in, const int* in_sizes, int n_in,
                              void* d_out, int out_size, void* d_ws, size_t ws_size,
                              hipStream_t stream)
{
  const float* x    = (const float*)d_in[0];
  const float* gw   = (const float*)d_in[1];
  const float* gb   = (const float*)d_in[2];
  const float* qkvw = (const float*)d_in[3];
  const float* qkvb = (const float*)d_in[4];
  const float* pw   = (const float*)d_in[5];
  const float* pb   = (const float*)d_in[6];
  float* out = (float*)d_out;

  u16* xn    = (u16*)d_ws;             // [b][n][c]
  u16* qkb   = xn   + 8388608;         // [b][n][1024]
  u16* vbf   = qkb  + 16777216;        // [b][dd][n'] (k-permuted 64-groups)
  u16* attb  = vbf  + 8388608;         // [b][n][c]
  u16* wq    = attb + 8388608;         // [1536][512]
  u16* wp    = wq   + 786432;          // [512][512]
  float* stats = (float*)(wp + 262144);  // [128][2] fp32

  hipMemsetAsync(stats, 0, 128 * 2 * sizeof(float), stream);
  gn_stats_cvt<<<2048, 256, 0, stream>>>(x, stats, qkvw, wq, pw, wp);
  gn_apply<<<2048, 256, 0, stream>>>(x, stats, gw, gb, xn);
  gemm_mfma<0><<<dim3(1536), 256, 0, stream>>>(
      wq, xn, qkvb, nullptr, qkb, vbf, nullptr);
  attn_mfma<<<dim3(1024), 256, 0, stream>>>(qkb, vbf, attb);
  gemm_mfma<1><<<dim3(512), 256, 0, stream>>>(
      wp, attb, pb, x, nullptr, nullptr, out);
}

// Round 12
// 194.705 us; speedup vs baseline: 1.1509x; 1.1509x over previous
//
#include <hip/hip_runtime.h>
#include <math.h>

typedef unsigned short u16;
typedef __attribute__((ext_vector_type(8))) short short8;    // 8 bf16 (4 VGPR)
typedef __attribute__((ext_vector_type(4))) float floatx4;
typedef __attribute__((ext_vector_type(4))) u16 v4u16;
typedef __attribute__((ext_vector_type(8))) u16 v8u16;

#define B_   16
#define C_   512
#define NSP  1024
#define EPSV 1e-5f
#define QSCALE 0.18033688011117f   // 0.125 * log2(e) — softmax in base 2

__device__ __forceinline__ u16 f2bf(float f) {
  union { float f; unsigned u; } v; v.f = f;
  unsigned r = v.u + 0x7FFFu + ((v.u >> 16) & 1u);   // RNE
  return (u16)(r >> 16);
}

__device__ __forceinline__ void gld16(const u16* g, u16* l) {
  __builtin_amdgcn_global_load_lds(
      (const __attribute__((address_space(1))) void*)g,
      (__attribute__((address_space(3))) void*)l, 16, 0, 0);
}

// inline-asm ds_read_b128 (R5, validated): invisible to alias analysis, so
// not ordered against outstanding global_load_lds. "=&v" early-clobber.
// Caller guarantees the buffer landed (explicit vmcnt/barrier protocol) and
// follows the group with s_waitcnt lgkmcnt(0) + sched_barrier(0) (rule #18).
__device__ __forceinline__ short8 lds_read_b128(const u16* p) {
  short8 r;
  asm volatile("ds_read_b128 %0, %1"
               : "=&v"(r)
               : "v"((const __attribute__((address_space(3))) u16*)p));
  return r;
}

// pack hi16(a)|hi16(b)<<16 : bf16 truncation pack, 1 instr
__device__ __forceinline__ unsigned pk_bf(float a, float b) {
  return __builtin_amdgcn_perm(__float_as_uint(b), __float_as_uint(a), 0x07060302u);
}

// ------- GroupNorm pass 1 + fp32->bf16 weight cvt, one launch (2048 blk) ---
__global__ __launch_bounds__(256) void gn_stats_cvt(
    const float* __restrict__ x, float* __restrict__ stats,
    const float* __restrict__ qa, u16* __restrict__ oa,     // 1536*512
    const float* __restrict__ pa, u16* __restrict__ ob)     // 512*512
{
  int blk = blockIdx.x;
  if (blk >= 1024) {               // ---- cvt path ----
    int cb = blk - 1024;
    const float* in; u16* out; int i;
    if (cb < 768) { in = qa; out = oa; i = (cb * 256 + threadIdx.x) * 4; }
    else          { in = pa; out = ob; i = ((cb - 768) * 256 + threadIdx.x) * 4; }
    float4 v = *(const float4*)(in + i);
    v4u16 o = { f2bf(v.x), f2bf(v.y), f2bf(v.z), f2bf(v.w) };
    *(v4u16*)(out + i) = o;
    return;
  }
  // ---- gn_stats path ----
  int bg = blk >> 3, ck = blk & 7;
  const float4* xp = (const float4*)(x + (((size_t)bg * 64 + ck * 8) * NSP));
  float s = 0.f, ss = 0.f;
#pragma unroll
  for (int it = 0; it < 8; ++it) {
    float4 v = xp[it * 256 + threadIdx.x];
    s  += v.x + v.y + v.z + v.w;
    ss += v.x * v.x + v.y * v.y + v.z * v.z + v.w * v.w;
  }
  for (int off = 32; off > 0; off >>= 1) {
    s  += __shfl_down(s, off);
    ss += __shfl_down(ss, off);
  }
  __shared__ float rs[4], rss[4];
  int lane = threadIdx.x & 63, wv = threadIdx.x >> 6;
  if (lane == 0) { rs[wv] = s; rss[wv] = ss; }
  __syncthreads();
  if (threadIdx.x == 0) {
    float S  = rs[0] + rs[1] + rs[2] + rs[3];
    float SS = rss[0] + rss[1] + rss[2] + rss[3];
    atomicAdd(&stats[bg * 2], S);
    atomicAdd(&stats[bg * 2 + 1], SS);
  }
}

// ------------- GroupNorm pass 2: normalize + transpose to [b][n][c] -------
__global__ __launch_bounds__(256) void gn_apply(
    const float* __restrict__ x, const float* __restrict__ stats,
    const float* __restrict__ gw, const float* __restrict__ gb,
    u16* __restrict__ xn)
{
  int blk = blockIdx.x;            // bg*16 + nt
  int bg = blk >> 4, nt = blk & 15;
  int b = bg >> 3, g = bg & 7;
  float S = stats[bg * 2], SS = stats[bg * 2 + 1];
  float mu  = S * (1.f / 65536.f);
  float var = SS * (1.f / 65536.f) - mu * mu;
  float inv = rsqrtf(var + EPSV);
  __shared__ float T[64][65];
  const float* xb = x + (size_t)bg * 64 * NSP;
  int t = threadIdx.x;
#pragma unroll
  for (int it = 0; it < 4; ++it) {
    int task = it * 256 + t;
    int cc = task >> 4, ns = task & 15;
    float4 v = *(const float4*)(xb + (size_t)cc * NSP + nt * 64 + ns * 4);
    T[cc][ns * 4 + 0] = v.x; T[cc][ns * 4 + 1] = v.y;
    T[cc][ns * 4 + 2] = v.z; T[cc][ns * 4 + 3] = v.w;
  }
  __syncthreads();
#pragma unroll
  for (int it = 0; it < 2; ++it) {
    int task = it * 256 + t;
    int n = task >> 3, cs = task & 7;
    v8u16 o;
#pragma unroll
    for (int u = 0; u < 8; ++u) {
      int cg = g * 64 + cs * 8 + u;
      float val = (T[cs * 8 + u][n] - mu) * inv * gw[cg] + gb[cg];
      o[u] = f2bf(val);
    }
    *(v8u16*)(xn + ((size_t)b * NSP + nt * 64 + n) * C_ + g * 64 + cs * 8) = o;
  }
}

// ---- bf16 MFMA GEMM: C[b][m][n] = W[m][k] * X[b][n][k]^T + bias[m] ----
// Flat 1D grid, id = y*128 + b*8 + x -> m-tiles sharing an X-panel share id%8
// (same XCD -> B-panel L2-resident).
// v9 (R8-validated; R9-R11 A-direct variant REVERTED — per-lane A loads are
// uncoalesced, 64 cache lines/wave vs 16, FETCH +15%, MfmaUtil 19->13.5):
// 3-stage counted-vmcnt pipeline + inline-asm ds_read_b128 frag loads
// (bypasses compiler's conservative vmcnt(0) drain after global_load_lds
// issue). Correctness held by explicit vmcnt(4)+s_barrier protocol;
// lgkmcnt(0)+sched_barrier(0) before MFMA (rule #18).
// MODE 0 (qkv): m<1024 -> out_qk[b][n][m] bf16 (Q rows scaled by QSCALE);
//               m>=1024 -> out_v[b][m-1024][n'] bf16, n' k-PERMUTED within
//               each 64-col group (k = (j&0x23)|((j&0x0C)<<1)|((j&0x10)>>2))
//               so attn PV A-frags are single ds_read_b128.
// MODE 1 (proj): out_f[b][m][n] fp32 = acc + bias + resid.
template <int MODE>
__global__ __launch_bounds__(256) void gemm_mfma(
    const u16* __restrict__ W, const u16* __restrict__ X,
    const float* __restrict__ bias, const float* __restrict__ resid,
    u16* __restrict__ out_qk, u16* __restrict__ out_v,
    float* __restrict__ out_f)
{
  __shared__ u16 smem[24576];      // 3 x 16KB stage buffers; epilogue overlays
  int id = blockIdx.x;
  int yb = id >> 7, rr = id & 127;
  int b = rr >> 3, xb_ = rr & 7;
  int m0 = yb * 128, n0 = xb_ * 128;
  int t = threadIdx.x, lane = t & 63, w = t >> 6;
  int c = lane & 15, q = lane >> 4;
  int wm = w >> 1, wn = w & 1;
  const u16* Xb = X + (size_t)b * NSP * C_;

  floatx4 acc[4][4];
#pragma unroll
  for (int mi = 0; mi < 4; ++mi)
#pragma unroll
    for (int ni = 0; ni < 4; ++ni) acc[mi][ni] = (floatx4){0.f, 0.f, 0.f, 0.f};

  auto stage = [&](int buf, int k0) {
    u16* Asb = smem + buf * 8192;
    u16* Bsb = Asb + 4096;
#pragma unroll
    for (int it = 0; it < 2; ++it) {
      int task = it * 256 + t;
      int mr = task >> 2;
      int gk = (task & 3) ^ ((mr >> 1) & 3);
      gld16(W + (size_t)(m0 + mr) * C_ + k0 + gk * 8, Asb + task * 8);
    }
#pragma unroll
    for (int it = 0; it < 2; ++it) {
      int task = it * 256 + t;
      int nr = task >> 2;
      int gk = (task & 3) ^ ((nr >> 1) & 3);
      gld16(Xb + (size_t)(n0 + nr) * C_ + k0 + gk * 8, Bsb + task * 8);
    }
  };

  auto compute = [&](int buf) {
    const u16* As = smem + buf * 8192;
    const u16* Bs = As + 4096;
    short8 af[4], bfr[4];
#pragma unroll
    for (int mi = 0; mi < 4; ++mi) {
      int m = wm * 64 + mi * 16 + c;
      af[mi] = lds_read_b128(As + m * 32 + ((q ^ ((m >> 1) & 3)) << 3));
    }
#pragma unroll
    for (int ni = 0; ni < 4; ++ni) {
      int n = wn * 64 + ni * 16 + c;
      bfr[ni] = lds_read_b128(Bs + n * 32 + ((q ^ ((n >> 1) & 3)) << 3));
    }
    asm volatile("s_waitcnt lgkmcnt(0)" ::: "memory");
    __builtin_amdgcn_sched_barrier(0);
#pragma unroll
    for (int mi = 0; mi < 4; ++mi)
#pragma unroll
      for (int ni = 0; ni < 4; ++ni)
        acc[mi][ni] = __builtin_amdgcn_mfma_f32_16x16x32_bf16(
            af[mi], bfr[ni], acc[mi][ni], 0, 0, 0);
  };

  stage(0, 0);
  stage(1, 32);
  int cur = 0, tgt = 2;
  for (int ki = 0; ki < 14; ++ki) {
    asm volatile("s_waitcnt vmcnt(4)" ::: "memory");
    __builtin_amdgcn_s_barrier();
    stage(tgt, (ki + 2) * 32);
    compute(cur);
    cur = (cur == 2) ? 0 : cur + 1;
    tgt = (tgt == 2) ? 0 : tgt + 1;
  }
  asm volatile("s_waitcnt vmcnt(4)" ::: "memory");
  __builtin_amdgcn_s_barrier();
  compute(2);                      // ki=14 -> buf 14%3 = 2
  asm volatile("s_waitcnt vmcnt(0)" ::: "memory");
  __builtin_amdgcn_s_barrier();
  compute(0);                      // ki=15 -> buf 15%3 = 0
  __syncthreads();                 // all waves out of buf0 before Cl overlay

  if (MODE == 0) {
    if (m0 < 1024) {       // Q/K region: transpose to [n][m] via LDS
      float sc = (m0 < 512) ? QSCALE : 1.0f;
      u16* Cl = smem;      // [128 n][136 m-stride]
#pragma unroll
      for (int mi = 0; mi < 4; ++mi) {
        floatx4 bi = *(const floatx4*)(bias + m0 + wm * 64 + mi * 16 + q * 4);
#pragma unroll
        for (int ni = 0; ni < 4; ++ni) {
          int n = wn * 64 + ni * 16 + c;
          int m = wm * 64 + mi * 16 + q * 4;
          v4u16 pk;
#pragma unroll
          for (int r = 0; r < 4; ++r) pk[r] = f2bf((acc[mi][ni][r] + bi[r]) * sc);
          *(v4u16*)(Cl + n * 136 + m) = pk;
        }
      }
      __syncthreads();
#pragma unroll
      for (int it = 0; it < 8; ++it) {
        int task = it * 256 + t;
        int n = task >> 4, seg = task & 15;
        v8u16 v = *(const v8u16*)(Cl + n * 136 + seg * 8);
        *(v8u16*)(out_qk + ((size_t)b * NSP + n0 + n) * 1024 + m0 + seg * 8) = v;
      }
    } else {               // V region: [m][n'] via LDS transpose, k-permuted
      u16* Cl = smem;      // [128 m][136 n-stride]
#pragma unroll
      for (int mi = 0; mi < 4; ++mi) {
        floatx4 bi = *(const floatx4*)(bias + m0 + wm * 64 + mi * 16 + q * 4);
#pragma unroll
        for (int ni = 0; ni < 4; ++ni) {
          int n = wn * 64 + ni * 16 + c;
          int m = wm * 64 + mi * 16 + q * 4;
#pragma unroll
          for (int r = 0; r < 4; ++r)
            Cl[(m + r) * 136 + n] = f2bf(acc[mi][ni][r] + bi[r]);
        }
      }
      __syncthreads();
      // store with per-64-group column permutation j -> k:
      // k = (j&0x23) | ((j&0x0C)<<1) | ((j&0x10)>>2).
      // source octet seg*8..+7 maps to two 4-runs at k0 and k0+8,
      // k0 = ((s&4)<<3) | ((s&1)<<4) | ((s&2)<<1), s = seg&7.
#pragma unroll
      for (int it = 0; it < 8; ++it) {
        int task = it * 256 + t;
        int m = task >> 4, seg = task & 15;
        int g64 = seg >> 3, s = seg & 7;
        int k0 = ((s & 4) << 3) | ((s & 1) << 4) | ((s & 2) << 1);
        v8u16 v = *(const v8u16*)(Cl + m * 136 + seg * 8);
        v4u16 lo = { v[0], v[1], v[2], v[3] };
        v4u16 hi = { v[4], v[5], v[6], v[7] };
        size_t base = ((size_t)b * C_ + m0 - 1024 + m) * NSP + n0 + g64 * 64;
        *(v4u16*)(out_v + base + k0) = lo;
        *(v4u16*)(out_v + base + k0 + 8) = hi;
      }
    }
  } else {                 // proj: fp32 [m][n] + bias + residual
#pragma unroll
    for (int mi = 0; mi < 4; ++mi) {
      floatx4 bi = *(const floatx4*)(bias + m0 + wm * 64 + mi * 16 + q * 4);
#pragma unroll
      for (int ni = 0; ni < 4; ++ni) {
        int n = n0 + wn * 64 + ni * 16 + c;
        int m = m0 + wm * 64 + mi * 16 + q * 4;
#pragma unroll
        for (int r = 0; r < 4; ++r) {
          size_t o = ((size_t)b * C_ + m + r) * NSP + n;
          out_f[o] = acc[mi][ni][r] + bi[r] + resid[o];
        }
      }
    }
  }
}

// ---- flash attention v10 (R8, validated): counted-vmcnt barriers (T4) ----
// 4 waves x 32 q-rows; jt2-interleaved QK/exp/PV; asm ds_read frags;
// denominator via mfma(ones,P); V k-permuted; s_setprio around PV.
// Loop protocol: issue prefetch -> vmcnt(4) (previous iter's loads only;
// this iter's 4 stay in flight across the barrier) -> compute -> raw
// s_barrier. Tail j0=15: vmcnt(0).
__global__ __launch_bounds__(256, 4) void attn_mfma(
    const u16* __restrict__ qk, const u16* __restrict__ vbuf,
    u16* __restrict__ att)
{
  __shared__ u16 __align__(16) smem[16384];   // 32 KB
  int id = blockIdx.x;
  int hb = id & 127;
  int i0 = id >> 7;
  int h = hb >> 4, b = hb & 15;
  int t = threadIdx.x, lane = t & 63, w = t >> 6;
  int c = lane & 15, q = lane >> 4;
  const u16* qbase = qk + (size_t)b * NSP * 1024;
  const u16* vbase = vbuf + (size_t)(b * C_ + h * 64) * NSP;

  // stage Q(128x64) -> [0..8192); K0 -> [8192..12288); V0 -> [12288..16384)
#pragma unroll
  for (int it = 0; it < 4; ++it) {
    int task = it * 256 + t;
    int r = task >> 3, seg = task & 7, ds = (seg ^ (r & 7)) * 8;
    gld16(qbase + (size_t)(i0 * 128 + r) * 1024 + h * 64 + ds, smem + task * 8);
  }
#pragma unroll
  for (int it = 0; it < 2; ++it) {
    int task = it * 256 + t;
    int r = task >> 3, seg = task & 7, ds = (seg ^ (r & 7)) * 8;
    gld16(qbase + (size_t)r * 1024 + 512 + h * 64 + ds, smem + 8192 + task * 8);
    gld16(vbase + (size_t)r * NSP + ds, smem + 12288 + task * 8);
  }
  __syncthreads();

  short8 qa[2][2];                 // rows w*32 + nf*16 + c
#pragma unroll
  for (int nf = 0; nf < 2; ++nf) {
    int row = w * 32 + nf * 16 + c;
#pragma unroll
    for (int ch = 0; ch < 2; ++ch)
      qa[nf][ch] = *(const short8*)(smem + row * 64 + (((q + 4 * ch) ^ (c & 7)) << 3));
  }
  __syncthreads();                 // all waves done reading Q before overlay

  short8 onesf;                    // all-ones bf16 A-operand (1.0 = 0x3F80)
#pragma unroll
  for (int u = 0; u < 8; ++u) onesf[u] = (short)0x3F80;

  floatx4 Oacc[4][2];              // [dt][nf]
  floatx4 OaccT[2];                // ones-MFMA column sums -> denominator
#pragma unroll
  for (int dt = 0; dt < 4; ++dt)
#pragma unroll
    for (int nf = 0; nf < 2; ++nf) Oacc[dt][nf] = (floatx4){0.f, 0.f, 0.f, 0.f};
#pragma unroll
  for (int nf = 0; nf < 2; ++nf) OaccT[nf] = (floatx4){0.f, 0.f, 0.f, 0.f};

  for (int j0 = 0; j0 < 16; ++j0) {
    int p = j0 & 1;
    u16* KS = smem + (p ? 0 : 8192);
    u16* VS = KS + 4096;
    if (j0 < 15) {                 // prefetch next K/V into the other parity
      u16* KN = smem + (p ? 8192 : 0);
      u16* VN = KN + 4096;
#pragma unroll
      for (int it = 0; it < 2; ++it) {
        int task = it * 256 + t;
        int r = task >> 3, seg = task & 7, ds = (seg ^ (r & 7)) * 8;
        gld16(qbase + (size_t)((j0 + 1) * 64 + r) * 1024 + 512 + h * 64 + ds,
              KN + task * 8);
        gld16(vbase + (size_t)r * NSP + (j0 + 1) * 64 + ds, VN + task * 8);
      }
      asm volatile("s_waitcnt vmcnt(4)" ::: "memory");
    } else {
      asm volatile("s_waitcnt vmcnt(0)" ::: "memory");   // tail: drain last
    }
    __builtin_amdgcn_sched_barrier(0);
#pragma unroll
    for (int jt2 = 0; jt2 < 2; ++jt2) {
      // --- batched asm frag reads: 4x K + 4x V, one lgkm wait ---
      short8 kb[2][2], vf[4];
#pragma unroll
      for (int jj = 0; jj < 2; ++jj) {
        int row = (jt2 * 2 + jj) * 16 + c;
        kb[jj][0] = lds_read_b128(KS + row * 64 + ((q ^ (row & 7)) << 3));
        kb[jj][1] = lds_read_b128(KS + row * 64 + (((q + 4) ^ (row & 7)) << 3));
      }
#pragma unroll
      for (int dt = 0; dt < 4; ++dt) {
        int dd = dt * 16 + c;
        vf[dt] = lds_read_b128(VS + dd * 64 + (((jt2 * 4 + q) ^ (dd & 7)) << 3));
      }
      asm volatile("s_waitcnt lgkmcnt(0)" ::: "memory");
      __builtin_amdgcn_sched_barrier(0);
      // --- QK half: S^T = K·Q^T for 32 j, base-2 exp, pack P bf16 ---
      unsigned pk2[2][2][2];
#pragma unroll
      for (int jj = 0; jj < 2; ++jj) {
#pragma unroll
        for (int nf = 0; nf < 2; ++nf) {
          floatx4 z = (floatx4){0.f, 0.f, 0.f, 0.f};
          z = __builtin_amdgcn_mfma_f32_16x16x32_bf16(kb[jj][0], qa[nf][0], z, 0, 0, 0);
          z = __builtin_amdgcn_mfma_f32_16x16x32_bf16(kb[jj][1], qa[nf][1], z, 0, 0, 0);
          float p0 = __builtin_amdgcn_exp2f(z[0]);
          float p1 = __builtin_amdgcn_exp2f(z[1]);
          float p2 = __builtin_amdgcn_exp2f(z[2]);
          float p3 = __builtin_amdgcn_exp2f(z[3]);
          pk2[jj][nf][0] = pk_bf(p0, p1);
          pk2[jj][nf][1] = pk_bf(p2, p3);
        }
      }
      short8 pf[2];
#pragma unroll
      for (int nf = 0; nf < 2; ++nf) {
        union { short8 s; unsigned d[4]; } u;
        u.d[0] = pk2[0][nf][0]; u.d[1] = pk2[0][nf][1];
        u.d[2] = pk2[1][nf][0]; u.d[3] = pk2[1][nf][1];
        pf[nf] = u.s;
      }
      // --- PV half: k-permuted V, all operands already in regs ---
      __builtin_amdgcn_s_setprio(1);
#pragma unroll
      for (int dt = 0; dt < 4; ++dt)
#pragma unroll
        for (int nf = 0; nf < 2; ++nf)
          Oacc[dt][nf] = __builtin_amdgcn_mfma_f32_16x16x32_bf16(
              vf[dt], pf[nf], Oacc[dt][nf], 0, 0, 0);
#pragma unroll
      for (int nf = 0; nf < 2; ++nf)
        OaccT[nf] = __builtin_amdgcn_mfma_f32_16x16x32_bf16(
            onesf, pf[nf], OaccT[nf], 0, 0, 0);
      __builtin_amdgcn_s_setprio(0);
    }
    __builtin_amdgcn_s_barrier();  // raw barrier: NO vmcnt drain (T4)
  }

  // ---- epilogue: denominator straight from ones-MFMA rows (all equal) ----
#pragma unroll
  for (int nf = 0; nf < 2; ++nf) {
    float rinv = 1.f / OaccT[nf][0];
    int n = i0 * 128 + w * 32 + nf * 16 + c;
#pragma unroll
    for (int dt = 0; dt < 4; ++dt) {
      v4u16 pk;
#pragma unroll
      for (int r = 0; r < 4; ++r) pk[r] = f2bf(Oacc[dt][nf][r] * rinv);
      *(v4u16*)(att + ((size_t)b * NSP + n) * C_ + h * 64 + dt * 16 + q * 4) = pk;
    }
  }
}

extern "C" void kernel_launch(void* const* d_in, const int* in_sizes, int n_in,
                              void* d_out, int out_size, void* d_ws, size_t ws_size,
                              hipStream_t stream)
{
  const float* x    = (const float*)d_in[0];
  const float* gw   = (const float*)d_in[1];
  const float* gb   = (const float*)d_in[2];
  const float* qkvw = (const float*)d_in[3];
  const float* qkvb = (const float*)d_in[4];
  const float* pw   = (const float*)d_in[5];
  const float* pb   = (const float*)d_in[6];
  float* out = (float*)d_out;

  u16* xn    = (u16*)d_ws;             // [b][n][c]
  u16* qkb   = xn   + 8388608;         // [b][n][1024]
  u16* vbf   = qkb  + 16777216;        // [b][dd][n'] (k-permuted 64-groups)
  u16* attb  = vbf  + 8388608;         // [b][n][c]
  u16* wq    = attb + 8388608;         // [1536][512]
  u16* wp    = wq   + 786432;          // [512][512]
  float* stats = (float*)(wp + 262144);  // [128][2] fp32

  hipMemsetAsync(stats, 0, 128 * 2 * sizeof(float), stream);
  gn_stats_cvt<<<2048, 256, 0, stream>>>(x, stats, qkvw, wq, pw, wp);
  gn_apply<<<2048, 256, 0, stream>>>(x, stats, gw, gb, xn);
  gemm_mfma<0><<<dim3(1536), 256, 0, stream>>>(
      wq, xn, qkvb, nullptr, qkb, vbf, nullptr);
  attn_mfma<<<dim3(1024), 256, 0, stream>>>(qkb, vbf, attb);
  gemm_mfma<1><<<dim3(512), 256, 0, stream>>>(
      wp, attb, pb, x, nullptr, nullptr, out);
}

// Round 13
// 189.734 us; speedup vs baseline: 1.1810x; 1.0262x over previous
//
#include <hip/hip_runtime.h>
#include <math.h>

typedef unsigned short u16;
typedef __attribute__((ext_vector_type(8))) short short8;    // 8 bf16 (4 VGPR)
typedef __attribute__((ext_vector_type(4))) float floatx4;
typedef __attribute__((ext_vector_type(4))) u16 v4u16;
typedef __attribute__((ext_vector_type(8))) u16 v8u16;

#define B_   16
#define C_   512
#define NSP  1024
#define EPSV 1e-5f
#define QSCALE 0.18033688011117f   // 0.125 * log2(e) — softmax in base 2

__device__ __forceinline__ u16 f2bf(float f) {
  union { float f; unsigned u; } v; v.f = f;
  unsigned r = v.u + 0x7FFFu + ((v.u >> 16) & 1u);   // RNE
  return (u16)(r >> 16);
}

__device__ __forceinline__ void gld16(const u16* g, u16* l) {
  __builtin_amdgcn_global_load_lds(
      (const __attribute__((address_space(1))) void*)g,
      (__attribute__((address_space(3))) void*)l, 16, 0, 0);
}

// inline-asm ds_read_b128 (R5, validated): invisible to alias analysis, so
// not ordered against outstanding global_load_lds. "=&v" early-clobber.
// Caller guarantees the buffer landed (explicit vmcnt/barrier protocol) and
// follows the group with a counted s_waitcnt lgkmcnt(N) + sched_barrier(0)
// before consuming (rule #18). DS ops retire IN ISSUE ORDER, so
// lgkmcnt(N) == "all but the newest N have landed".
__device__ __forceinline__ short8 lds_read_b128(const u16* p) {
  short8 r;
  asm volatile("ds_read_b128 %0, %1"
               : "=&v"(r)
               : "v"((const __attribute__((address_space(3))) u16*)p));
  return r;
}

// pack hi16(a)|hi16(b)<<16 : bf16 truncation pack, 1 instr
__device__ __forceinline__ unsigned pk_bf(float a, float b) {
  return __builtin_amdgcn_perm(__float_as_uint(b), __float_as_uint(a), 0x07060302u);
}

// ------- GroupNorm pass 1 + fp32->bf16 weight cvt, one launch (2048 blk) ---
__global__ __launch_bounds__(256) void gn_stats_cvt(
    const float* __restrict__ x, float* __restrict__ stats,
    const float* __restrict__ qa, u16* __restrict__ oa,     // 1536*512
    const float* __restrict__ pa, u16* __restrict__ ob)     // 512*512
{
  int blk = blockIdx.x;
  if (blk >= 1024) {               // ---- cvt path ----
    int cb = blk - 1024;
    const float* in; u16* out; int i;
    if (cb < 768) { in = qa; out = oa; i = (cb * 256 + threadIdx.x) * 4; }
    else          { in = pa; out = ob; i = ((cb - 768) * 256 + threadIdx.x) * 4; }
    float4 v = *(const float4*)(in + i);
    v4u16 o = { f2bf(v.x), f2bf(v.y), f2bf(v.z), f2bf(v.w) };
    *(v4u16*)(out + i) = o;
    return;
  }
  // ---- gn_stats path ----
  int bg = blk >> 3, ck = blk & 7;
  const float4* xp = (const float4*)(x + (((size_t)bg * 64 + ck * 8) * NSP));
  float s = 0.f, ss = 0.f;
#pragma unroll
  for (int it = 0; it < 8; ++it) {
    float4 v = xp[it * 256 + threadIdx.x];
    s  += v.x + v.y + v.z + v.w;
    ss += v.x * v.x + v.y * v.y + v.z * v.z + v.w * v.w;
  }
  for (int off = 32; off > 0; off >>= 1) {
    s  += __shfl_down(s, off);
    ss += __shfl_down(ss, off);
  }
  __shared__ float rs[4], rss[4];
  int lane = threadIdx.x & 63, wv = threadIdx.x >> 6;
  if (lane == 0) { rs[wv] = s; rss[wv] = ss; }
  __syncthreads();
  if (threadIdx.x == 0) {
    float S  = rs[0] + rs[1] + rs[2] + rs[3];
    float SS = rss[0] + rss[1] + rss[2] + rss[3];
    atomicAdd(&stats[bg * 2], S);
    atomicAdd(&stats[bg * 2 + 1], SS);
  }
}

// ------------- GroupNorm pass 2: normalize + transpose to [b][n][c] -------
__global__ __launch_bounds__(256) void gn_apply(
    const float* __restrict__ x, const float* __restrict__ stats,
    const float* __restrict__ gw, const float* __restrict__ gb,
    u16* __restrict__ xn)
{
  int blk = blockIdx.x;            // bg*16 + nt
  int bg = blk >> 4, nt = blk & 15;
  int b = bg >> 3, g = bg & 7;
  float S = stats[bg * 2], SS = stats[bg * 2 + 1];
  float mu  = S * (1.f / 65536.f);
  float var = SS * (1.f / 65536.f) - mu * mu;
  float inv = rsqrtf(var + EPSV);
  __shared__ float T[64][65];
  const float* xb = x + (size_t)bg * 64 * NSP;
  int t = threadIdx.x;
#pragma unroll
  for (int it = 0; it < 4; ++it) {
    int task = it * 256 + t;
    int cc = task >> 4, ns = task & 15;
    float4 v = *(const float4*)(xb + (size_t)cc * NSP + nt * 64 + ns * 4);
    T[cc][ns * 4 + 0] = v.x; T[cc][ns * 4 + 1] = v.y;
    T[cc][ns * 4 + 2] = v.z; T[cc][ns * 4 + 3] = v.w;
  }
  __syncthreads();
#pragma unroll
  for (int it = 0; it < 2; ++it) {
    int task = it * 256 + t;
    int n = task >> 3, cs = task & 7;
    v8u16 o;
#pragma unroll
    for (int u = 0; u < 8; ++u) {
      int cg = g * 64 + cs * 8 + u;
      float val = (T[cs * 8 + u][n] - mu) * inv * gw[cg] + gb[cg];
      o[u] = f2bf(val);
    }
    *(v8u16*)(xn + ((size_t)b * NSP + nt * 64 + n) * C_ + g * 64 + cs * 8) = o;
  }
}

// ---- bf16 MFMA GEMM: C[b][m][n] = W[m][k] * X[b][n][k]^T + bias[m] ----
// Flat 1D grid, id = y*128 + b*8 + x -> m-tiles sharing an X-panel share id%8
// (same XCD -> B-panel L2-resident).
// v9b (R8-validated v9 + R13 split-wait): 3-stage counted-vmcnt pipeline +
// inline-asm ds_read_b128 frag loads. NEW: reads issued in two groups
// {af0,af1,bfr0,bfr1 | af2,af3,bfr2,bfr3}; lgkmcnt(4) covers group 1 ->
// 4 MFMAs of the (0-1)x(0-1) quadrant run while group 2's reads land ->
// lgkmcnt(0) -> remaining 12. s_setprio(1) around MFMA clusters (T5 —
// counted-vmcnt waves are de-lockstepped, m190's null condition gone).
// MODE 0 (qkv): m<1024 -> out_qk[b][n][m] bf16 (Q rows scaled by QSCALE);
//               m>=1024 -> out_v[b][m-1024][n'] bf16, n' k-PERMUTED within
//               each 64-col group (k = (j&0x23)|((j&0x0C)<<1)|((j&0x10)>>2))
//               so attn PV A-frags are single ds_read_b128.
// MODE 1 (proj): out_f[b][m][n] fp32 = acc + bias + resid.
template <int MODE>
__global__ __launch_bounds__(256) void gemm_mfma(
    const u16* __restrict__ W, const u16* __restrict__ X,
    const float* __restrict__ bias, const float* __restrict__ resid,
    u16* __restrict__ out_qk, u16* __restrict__ out_v,
    float* __restrict__ out_f)
{
  __shared__ u16 smem[24576];      // 3 x 16KB stage buffers; epilogue overlays
  int id = blockIdx.x;
  int yb = id >> 7, rr = id & 127;
  int b = rr >> 3, xb_ = rr & 7;
  int m0 = yb * 128, n0 = xb_ * 128;
  int t = threadIdx.x, lane = t & 63, w = t >> 6;
  int c = lane & 15, q = lane >> 4;
  int wm = w >> 1, wn = w & 1;
  const u16* Xb = X + (size_t)b * NSP * C_;

  floatx4 acc[4][4];
#pragma unroll
  for (int mi = 0; mi < 4; ++mi)
#pragma unroll
    for (int ni = 0; ni < 4; ++ni) acc[mi][ni] = (floatx4){0.f, 0.f, 0.f, 0.f};

  auto stage = [&](int buf, int k0) {
    u16* Asb = smem + buf * 8192;
    u16* Bsb = Asb + 4096;
#pragma unroll
    for (int it = 0; it < 2; ++it) {
      int task = it * 256 + t;
      int mr = task >> 2;
      int gk = (task & 3) ^ ((mr >> 1) & 3);
      gld16(W + (size_t)(m0 + mr) * C_ + k0 + gk * 8, Asb + task * 8);
    }
#pragma unroll
    for (int it = 0; it < 2; ++it) {
      int task = it * 256 + t;
      int nr = task >> 2;
      int gk = (task & 3) ^ ((nr >> 1) & 3);
      gld16(Xb + (size_t)(n0 + nr) * C_ + k0 + gk * 8, Bsb + task * 8);
    }
  };

  auto compute = [&](int buf) {
    const u16* As = smem + buf * 8192;
    const u16* Bs = As + 4096;
    short8 af[4], bfr[4];
    // group 1: af0, af1, bfr0, bfr1  (issue order = retire order for DS)
#pragma unroll
    for (int mi = 0; mi < 2; ++mi) {
      int m = wm * 64 + mi * 16 + c;
      af[mi] = lds_read_b128(As + m * 32 + ((q ^ ((m >> 1) & 3)) << 3));
    }
#pragma unroll
    for (int ni = 0; ni < 2; ++ni) {
      int n = wn * 64 + ni * 16 + c;
      bfr[ni] = lds_read_b128(Bs + n * 32 + ((q ^ ((n >> 1) & 3)) << 3));
    }
    // group 2: af2, af3, bfr2, bfr3
#pragma unroll
    for (int mi = 2; mi < 4; ++mi) {
      int m = wm * 64 + mi * 16 + c;
      af[mi] = lds_read_b128(As + m * 32 + ((q ^ ((m >> 1) & 3)) << 3));
    }
#pragma unroll
    for (int ni = 2; ni < 4; ++ni) {
      int n = wn * 64 + ni * 16 + c;
      bfr[ni] = lds_read_b128(Bs + n * 32 + ((q ^ ((n >> 1) & 3)) << 3));
    }
    // group 1 landed (4 newest outstanding = group 2)
    asm volatile("s_waitcnt lgkmcnt(4)" ::: "memory");
    __builtin_amdgcn_sched_barrier(0);
    __builtin_amdgcn_s_setprio(1);
#pragma unroll
    for (int mi = 0; mi < 2; ++mi)
#pragma unroll
      for (int ni = 0; ni < 2; ++ni)
        acc[mi][ni] = __builtin_amdgcn_mfma_f32_16x16x32_bf16(
            af[mi], bfr[ni], acc[mi][ni], 0, 0, 0);
    __builtin_amdgcn_s_setprio(0);
    asm volatile("s_waitcnt lgkmcnt(0)" ::: "memory");
    __builtin_amdgcn_sched_barrier(0);
    __builtin_amdgcn_s_setprio(1);
#pragma unroll
    for (int mi = 0; mi < 4; ++mi)
#pragma unroll
      for (int ni = 0; ni < 4; ++ni)
        if (mi >= 2 || ni >= 2)
          acc[mi][ni] = __builtin_amdgcn_mfma_f32_16x16x32_bf16(
              af[mi], bfr[ni], acc[mi][ni], 0, 0, 0);
    __builtin_amdgcn_s_setprio(0);
  };

  stage(0, 0);
  stage(1, 32);
  int cur = 0, tgt = 2;
  for (int ki = 0; ki < 14; ++ki) {
    asm volatile("s_waitcnt vmcnt(4)" ::: "memory");
    __builtin_amdgcn_s_barrier();
    stage(tgt, (ki + 2) * 32);
    compute(cur);
    cur = (cur == 2) ? 0 : cur + 1;
    tgt = (tgt == 2) ? 0 : tgt + 1;
  }
  asm volatile("s_waitcnt vmcnt(4)" ::: "memory");
  __builtin_amdgcn_s_barrier();
  compute(2);                      // ki=14 -> buf 14%3 = 2
  asm volatile("s_waitcnt vmcnt(0)" ::: "memory");
  __builtin_amdgcn_s_barrier();
  compute(0);                      // ki=15 -> buf 15%3 = 0
  __syncthreads();                 // all waves out of buf0 before Cl overlay

  if (MODE == 0) {
    if (m0 < 1024) {       // Q/K region: transpose to [n][m] via LDS
      float sc = (m0 < 512) ? QSCALE : 1.0f;
      u16* Cl = smem;      // [128 n][136 m-stride]
#pragma unroll
      for (int mi = 0; mi < 4; ++mi) {
        floatx4 bi = *(const floatx4*)(bias + m0 + wm * 64 + mi * 16 + q * 4);
#pragma unroll
        for (int ni = 0; ni < 4; ++ni) {
          int n = wn * 64 + ni * 16 + c;
          int m = wm * 64 + mi * 16 + q * 4;
          v4u16 pk;
#pragma unroll
          for (int r = 0; r < 4; ++r) pk[r] = f2bf((acc[mi][ni][r] + bi[r]) * sc);
          *(v4u16*)(Cl + n * 136 + m) = pk;
        }
      }
      __syncthreads();
#pragma unroll
      for (int it = 0; it < 8; ++it) {
        int task = it * 256 + t;
        int n = task >> 4, seg = task & 15;
        v8u16 v = *(const v8u16*)(Cl + n * 136 + seg * 8);
        *(v8u16*)(out_qk + ((size_t)b * NSP + n0 + n) * 1024 + m0 + seg * 8) = v;
      }
    } else {               // V region: [m][n'] via LDS transpose, k-permuted
      u16* Cl = smem;      // [128 m][136 n-stride]
#pragma unroll
      for (int mi = 0; mi < 4; ++mi) {
        floatx4 bi = *(const floatx4*)(bias + m0 + wm * 64 + mi * 16 + q * 4);
#pragma unroll
        for (int ni = 0; ni < 4; ++ni) {
          int n = wn * 64 + ni * 16 + c;
          int m = wm * 64 + mi * 16 + q * 4;
#pragma unroll
          for (int r = 0; r < 4; ++r)
            Cl[(m + r) * 136 + n] = f2bf(acc[mi][ni][r] + bi[r]);
        }
      }
      __syncthreads();
      // store with per-64-group column permutation j -> k:
      // k = (j&0x23) | ((j&0x0C)<<1) | ((j&0x10)>>2).
      // source octet seg*8..+7 maps to two 4-runs at k0 and k0+8,
      // k0 = ((s&4)<<3) | ((s&1)<<4) | ((s&2)<<1), s = seg&7.
#pragma unroll
      for (int it = 0; it < 8; ++it) {
        int task = it * 256 + t;
        int m = task >> 4, seg = task & 15;
        int g64 = seg >> 3, s = seg & 7;
        int k0 = ((s & 4) << 3) | ((s & 1) << 4) | ((s & 2) << 1);
        v8u16 v = *(const v8u16*)(Cl + m * 136 + seg * 8);
        v4u16 lo = { v[0], v[1], v[2], v[3] };
        v4u16 hi = { v[4], v[5], v[6], v[7] };
        size_t base = ((size_t)b * C_ + m0 - 1024 + m) * NSP + n0 + g64 * 64;
        *(v4u16*)(out_v + base + k0) = lo;
        *(v4u16*)(out_v + base + k0 + 8) = hi;
      }
    }
  } else {                 // proj: fp32 [m][n] + bias + residual
#pragma unroll
    for (int mi = 0; mi < 4; ++mi) {
      floatx4 bi = *(const floatx4*)(bias + m0 + wm * 64 + mi * 16 + q * 4);
#pragma unroll
      for (int ni = 0; ni < 4; ++ni) {
        int n = n0 + wn * 64 + ni * 16 + c;
        int m = m0 + wm * 64 + mi * 16 + q * 4;
#pragma unroll
        for (int r = 0; r < 4; ++r) {
          size_t o = ((size_t)b * C_ + m + r) * NSP + n;
          out_f[o] = acc[mi][ni][r] + bi[r] + resid[o];
        }
      }
    }
  }
}

// ---- flash attention v10b (R8 v10 + R13 split-wait) ----
// 4 waves x 32 q-rows; jt2-interleaved QK/exp/PV; asm ds_read frags;
// denominator via mfma(ones,P); V k-permuted; s_setprio around PV.
// Loop protocol: issue prefetch -> vmcnt(4) (previous iter's loads only;
// this iter's 4 stay in flight across the barrier) -> compute -> raw
// s_barrier. Tail j0=15: vmcnt(0).
// NEW: K-reads and V-reads issued together, but the wait is SPLIT —
// lgkmcnt(4) (K landed, V in flight) before QK/exp/pack; lgkmcnt(0) only
// before PV. V-read latency hides under the exp chain.
__global__ __launch_bounds__(256, 4) void attn_mfma(
    const u16* __restrict__ qk, const u16* __restrict__ vbuf,
    u16* __restrict__ att)
{
  __shared__ u16 __align__(16) smem[16384];   // 32 KB
  int id = blockIdx.x;
  int hb = id & 127;
  int i0 = id >> 7;
  int h = hb >> 4, b = hb & 15;
  int t = threadIdx.x, lane = t & 63, w = t >> 6;
  int c = lane & 15, q = lane >> 4;
  const u16* qbase = qk + (size_t)b * NSP * 1024;
  const u16* vbase = vbuf + (size_t)(b * C_ + h * 64) * NSP;

  // stage Q(128x64) -> [0..8192); K0 -> [8192..12288); V0 -> [12288..16384)
#pragma unroll
  for (int it = 0; it < 4; ++it) {
    int task = it * 256 + t;
    int r = task >> 3, seg = task & 7, ds = (seg ^ (r & 7)) * 8;
    gld16(qbase + (size_t)(i0 * 128 + r) * 1024 + h * 64 + ds, smem + task * 8);
  }
#pragma unroll
  for (int it = 0; it < 2; ++it) {
    int task = it * 256 + t;
    int r = task >> 3, seg = task & 7, ds = (seg ^ (r & 7)) * 8;
    gld16(qbase + (size_t)r * 1024 + 512 + h * 64 + ds, smem + 8192 + task * 8);
    gld16(vbase + (size_t)r * NSP + ds, smem + 12288 + task * 8);
  }
  __syncthreads();

  short8 qa[2][2];                 // rows w*32 + nf*16 + c
#pragma unroll
  for (int nf = 0; nf < 2; ++nf) {
    int row = w * 32 + nf * 16 + c;
#pragma unroll
    for (int ch = 0; ch < 2; ++ch)
      qa[nf][ch] = *(const short8*)(smem + row * 64 + (((q + 4 * ch) ^ (c & 7)) << 3));
  }
  __syncthreads();                 // all waves done reading Q before overlay

  short8 onesf;                    // all-ones bf16 A-operand (1.0 = 0x3F80)
#pragma unroll
  for (int u = 0; u < 8; ++u) onesf[u] = (short)0x3F80;

  floatx4 Oacc[4][2];              // [dt][nf]
  floatx4 OaccT[2];                // ones-MFMA column sums -> denominator
#pragma unroll
  for (int dt = 0; dt < 4; ++dt)
#pragma unroll
    for (int nf = 0; nf < 2; ++nf) Oacc[dt][nf] = (floatx4){0.f, 0.f, 0.f, 0.f};
#pragma unroll
  for (int nf = 0; nf < 2; ++nf) OaccT[nf] = (floatx4){0.f, 0.f, 0.f, 0.f};

  for (int j0 = 0; j0 < 16; ++j0) {
    int p = j0 & 1;
    u16* KS = smem + (p ? 0 : 8192);
    u16* VS = KS + 4096;
    if (j0 < 15) {                 // prefetch next K/V into the other parity
      u16* KN = smem + (p ? 8192 : 0);
      u16* VN = KN + 4096;
#pragma unroll
      for (int it = 0; it < 2; ++it) {
        int task = it * 256 + t;
        int r = task >> 3, seg = task & 7, ds = (seg ^ (r & 7)) * 8;
        gld16(qbase + (size_t)((j0 + 1) * 64 + r) * 1024 + 512 + h * 64 + ds,
              KN + task * 8);
        gld16(vbase + (size_t)r * NSP + (j0 + 1) * 64 + ds, VN + task * 8);
      }
      asm volatile("s_waitcnt vmcnt(4)" ::: "memory");
    } else {
      asm volatile("s_waitcnt vmcnt(0)" ::: "memory");   // tail: drain last
    }
    __builtin_amdgcn_sched_barrier(0);
#pragma unroll
    for (int jt2 = 0; jt2 < 2; ++jt2) {
      // --- asm frag reads: 4x K then 4x V (issue order = retire order) ---
      short8 kb[2][2], vf[4];
#pragma unroll
      for (int jj = 0; jj < 2; ++jj) {
        int row = (jt2 * 2 + jj) * 16 + c;
        kb[jj][0] = lds_read_b128(KS + row * 64 + ((q ^ (row & 7)) << 3));
        kb[jj][1] = lds_read_b128(KS + row * 64 + (((q + 4) ^ (row & 7)) << 3));
      }
#pragma unroll
      for (int dt = 0; dt < 4; ++dt) {
        int dd = dt * 16 + c;
        vf[dt] = lds_read_b128(VS + dd * 64 + (((jt2 * 4 + q) ^ (dd & 7)) << 3));
      }
      // split wait: K landed (V's 4 reads still in flight)
      asm volatile("s_waitcnt lgkmcnt(4)" ::: "memory");
      __builtin_amdgcn_sched_barrier(0);
      // --- QK half: S^T = K·Q^T for 32 j, base-2 exp, pack P bf16 ---
      //     (V reads land underneath this exp chain)
      unsigned pk2[2][2][2];
#pragma unroll
      for (int jj = 0; jj < 2; ++jj) {
#pragma unroll
        for (int nf = 0; nf < 2; ++nf) {
          floatx4 z = (floatx4){0.f, 0.f, 0.f, 0.f};
          z = __builtin_amdgcn_mfma_f32_16x16x32_bf16(kb[jj][0], qa[nf][0], z, 0, 0, 0);
          z = __builtin_amdgcn_mfma_f32_16x16x32_bf16(kb[jj][1], qa[nf][1], z, 0, 0, 0);
          float p0 = __builtin_amdgcn_exp2f(z[0]);
          float p1 = __builtin_amdgcn_exp2f(z[1]);
          float p2 = __builtin_amdgcn_exp2f(z[2]);
          float p3 = __builtin_amdgcn_exp2f(z[3]);
          pk2[jj][nf][0] = pk_bf(p0, p1);
          pk2[jj][nf][1] = pk_bf(p2, p3);
        }
      }
      short8 pf[2];
#pragma unroll
      for (int nf = 0; nf < 2; ++nf) {
        union { short8 s; unsigned d[4]; } u;
        u.d[0] = pk2[0][nf][0]; u.d[1] = pk2[0][nf][1];
        u.d[2] = pk2[1][nf][0]; u.d[3] = pk2[1][nf][1];
        pf[nf] = u.s;
      }
      // --- PV half: wait V reads, then k-permuted V MFMAs ---
      asm volatile("s_waitcnt lgkmcnt(0)" ::: "memory");
      __builtin_amdgcn_sched_barrier(0);
      __builtin_amdgcn_s_setprio(1);
#pragma unroll
      for (int dt = 0; dt < 4; ++dt)
#pragma unroll
        for (int nf = 0; nf < 2; ++nf)
          Oacc[dt][nf] = __builtin_amdgcn_mfma_f32_16x16x32_bf16(
              vf[dt], pf[nf], Oacc[dt][nf], 0, 0, 0);
#pragma unroll
      for (int nf = 0; nf < 2; ++nf)
        OaccT[nf] = __builtin_amdgcn_mfma_f32_16x16x32_bf16(
            onesf, pf[nf], OaccT[nf], 0, 0, 0);
      __builtin_amdgcn_s_setprio(0);
    }
    __builtin_amdgcn_s_barrier();  // raw barrier: NO vmcnt drain (T4)
  }

  // ---- epilogue: denominator straight from ones-MFMA rows (all equal) ----
#pragma unroll
  for (int nf = 0; nf < 2; ++nf) {
    float rinv = 1.f / OaccT[nf][0];
    int n = i0 * 128 + w * 32 + nf * 16 + c;
#pragma unroll
    for (int dt = 0; dt < 4; ++dt) {
      v4u16 pk;
#pragma unroll
      for (int r = 0; r < 4; ++r) pk[r] = f2bf(Oacc[dt][nf][r] * rinv);
      *(v4u16*)(att + ((size_t)b * NSP + n) * C_ + h * 64 + dt * 16 + q * 4) = pk;
    }
  }
}

extern "C" void kernel_launch(void* const* d_in, const int* in_sizes, int n_in,
                              void* d_out, int out_size, void* d_ws, size_t ws_size,
                              hipStream_t stream)
{
  const float* x    = (const float*)d_in[0];
  const float* gw   = (const float*)d_in[1];
  const float* gb   = (const float*)d_in[2];
  const float* qkvw = (const float*)d_in[3];
  const float* qkvb = (const float*)d_in[4];
  const float* pw   = (const float*)d_in[5];
  const float* pb   = (const float*)d_in[6];
  float* out = (float*)d_out;

  u16* xn    = (u16*)d_ws;             // [b][n][c]
  u16* qkb   = xn   + 8388608;         // [b][n][1024]
  u16* vbf   = qkb  + 16777216;        // [b][dd][n'] (k-permuted 64-groups)
  u16* attb  = vbf  + 8388608;         // [b][n][c]
  u16* wq    = attb + 8388608;         // [1536][512]
  u16* wp    = wq   + 786432;          // [512][512]
  float* stats = (float*)(wp + 262144);  // [128][2] fp32

  hipMemsetAsync(stats, 0, 128 * 2 * sizeof(float), stream);
  gn_stats_cvt<<<2048, 256, 0, stream>>>(x, stats, qkvw, wq, pw, wp);
  gn_apply<<<2048, 256, 0, stream>>>(x, stats, gw, gb, xn);
  gemm_mfma<0><<<dim3(1536), 256, 0, stream>>>(
      wq, xn, qkvb, nullptr, qkb, vbf, nullptr);
  attn_mfma<<<dim3(1024), 256, 0, stream>>>(qkb, vbf, attb);
  gemm_mfma<1><<<dim3(512), 256, 0, stream>>>(
      wp, attb, pb, x, nullptr, nullptr, out);
}

// Round 14
// 188.823 us; speedup vs baseline: 1.1867x; 1.0048x over previous
//
#include <hip/hip_runtime.h>
#include <math.h>

typedef unsigned short u16;
typedef __attribute__((ext_vector_type(8))) short short8;    // 8 bf16 (4 VGPR)
typedef __attribute__((ext_vector_type(4))) float floatx4;
typedef __attribute__((ext_vector_type(4))) u16 v4u16;
typedef __attribute__((ext_vector_type(8))) u16 v8u16;

#define B_   16
#define C_   512
#define NSP  1024
#define EPSV 1e-5f
#define QSCALE 0.18033688011117f   // 0.125 * log2(e) — softmax in base 2

__device__ __forceinline__ u16 f2bf(float f) {
  union { float f; unsigned u; } v; v.f = f;
  unsigned r = v.u + 0x7FFFu + ((v.u >> 16) & 1u);   // RNE
  return (u16)(r >> 16);
}

__device__ __forceinline__ void gld16(const u16* g, u16* l) {
  __builtin_amdgcn_global_load_lds(
      (const __attribute__((address_space(1))) void*)g,
      (__attribute__((address_space(3))) void*)l, 16, 0, 0);
}

// inline-asm ds_read_b128 (R5, validated): invisible to alias analysis, so
// not ordered against outstanding global_load_lds. "=&v" early-clobber.
// Caller guarantees the buffer landed (explicit vmcnt/barrier protocol) and
// follows the group with a counted s_waitcnt lgkmcnt(N) + sched_barrier(0)
// before consuming (rule #18). DS ops retire IN ISSUE ORDER, so
// lgkmcnt(N) == "all but the newest N have landed".
__device__ __forceinline__ short8 lds_read_b128(const u16* p) {
  short8 r;
  asm volatile("ds_read_b128 %0, %1"
               : "=&v"(r)
               : "v"((const __attribute__((address_space(3))) u16*)p));
  return r;
}

// pack hi16(a)|hi16(b)<<16 : bf16 truncation pack, 1 instr
__device__ __forceinline__ unsigned pk_bf(float a, float b) {
  return __builtin_amdgcn_perm(__float_as_uint(b), __float_as_uint(a), 0x07060302u);
}

// ------- GroupNorm pass 1 + fp32->bf16 weight cvt, one launch (2048 blk) ---
__global__ __launch_bounds__(256) void gn_stats_cvt(
    const float* __restrict__ x, float* __restrict__ stats,
    const float* __restrict__ qa, u16* __restrict__ oa,     // 1536*512
    const float* __restrict__ pa, u16* __restrict__ ob)     // 512*512
{
  int blk = blockIdx.x;
  if (blk >= 1024) {               // ---- cvt path ----
    int cb = blk - 1024;
    const float* in; u16* out; int i;
    if (cb < 768) { in = qa; out = oa; i = (cb * 256 + threadIdx.x) * 4; }
    else          { in = pa; out = ob; i = ((cb - 768) * 256 + threadIdx.x) * 4; }
    float4 v = *(const float4*)(in + i);
    v4u16 o = { f2bf(v.x), f2bf(v.y), f2bf(v.z), f2bf(v.w) };
    *(v4u16*)(out + i) = o;
    return;
  }
  // ---- gn_stats path ----
  int bg = blk >> 3, ck = blk & 7;
  const float4* xp = (const float4*)(x + (((size_t)bg * 64 + ck * 8) * NSP));
  float s = 0.f, ss = 0.f;
#pragma unroll
  for (int it = 0; it < 8; ++it) {
    float4 v = xp[it * 256 + threadIdx.x];
    s  += v.x + v.y + v.z + v.w;
    ss += v.x * v.x + v.y * v.y + v.z * v.z + v.w * v.w;
  }
  for (int off = 32; off > 0; off >>= 1) {
    s  += __shfl_down(s, off);
    ss += __shfl_down(ss, off);
  }
  __shared__ float rs[4], rss[4];
  int lane = threadIdx.x & 63, wv = threadIdx.x >> 6;
  if (lane == 0) { rs[wv] = s; rss[wv] = ss; }
  __syncthreads();
  if (threadIdx.x == 0) {
    float S  = rs[0] + rs[1] + rs[2] + rs[3];
    float SS = rss[0] + rss[1] + rss[2] + rss[3];
    atomicAdd(&stats[bg * 2], S);
    atomicAdd(&stats[bg * 2 + 1], SS);
  }
}

// ------------- GroupNorm pass 2: normalize + transpose to [b][n][c] -------
__global__ __launch_bounds__(256) void gn_apply(
    const float* __restrict__ x, const float* __restrict__ stats,
    const float* __restrict__ gw, const float* __restrict__ gb,
    u16* __restrict__ xn)
{
  int blk = blockIdx.x;            // bg*16 + nt
  int bg = blk >> 4, nt = blk & 15;
  int b = bg >> 3, g = bg & 7;
  float S = stats[bg * 2], SS = stats[bg * 2 + 1];
  float mu  = S * (1.f / 65536.f);
  float var = SS * (1.f / 65536.f) - mu * mu;
  float inv = rsqrtf(var + EPSV);
  __shared__ float T[64][65];
  const float* xb = x + (size_t)bg * 64 * NSP;
  int t = threadIdx.x;
#pragma unroll
  for (int it = 0; it < 4; ++it) {
    int task = it * 256 + t;
    int cc = task >> 4, ns = task & 15;
    float4 v = *(const float4*)(xb + (size_t)cc * NSP + nt * 64 + ns * 4);
    T[cc][ns * 4 + 0] = v.x; T[cc][ns * 4 + 1] = v.y;
    T[cc][ns * 4 + 2] = v.z; T[cc][ns * 4 + 3] = v.w;
  }
  __syncthreads();
#pragma unroll
  for (int it = 0; it < 2; ++it) {
    int task = it * 256 + t;
    int n = task >> 3, cs = task & 7;
    v8u16 o;
#pragma unroll
    for (int u = 0; u < 8; ++u) {
      int cg = g * 64 + cs * 8 + u;
      float val = (T[cs * 8 + u][n] - mu) * inv * gw[cg] + gb[cg];
      o[u] = f2bf(val);
    }
    *(v8u16*)(xn + ((size_t)b * NSP + nt * 64 + n) * C_ + g * 64 + cs * 8) = o;
  }
}

// ---- bf16 MFMA GEMM: C[b][m][n] = W[m][k] * X[b][n][k]^T + bias[m] ----
// v9c = R13-validated v9b + panel-complete residency halves for MODE 0.
// R13 profile: FETCH 31.4MB vs 18.3MB minimum — grid 1536 at 3 blocks/CU
// = 768 resident => TWO dispatch rounds; old id=y*128+(b,x) put y=0..5 in
// round 1 and y=6..11 in round 2, so every X-panel was HBM-fetched twice.
// New MODE-0 map: id = half*768 + y*64 + b*4 + x4, x = half*4 + x4 —
// each 768-id residency half contains ALL 12 y-tiles of its 64 (b,x)
// panels => X fetched once. Bijection: 2*12*16*4 = 1536. XCD property
// kept: same-(b,x) => same id%8 (768,64 = 0 mod 8). MODE 1 (512 blocks =
// single round) keeps the old map.
// Body (R13): 3-stage counted-vmcnt pipeline + asm ds_read frag loads,
// split lgkmcnt(4)/(0) waits, s_setprio around MFMA clusters.
// MODE 0 (qkv): m<1024 -> out_qk[b][n][m] bf16 (Q rows scaled by QSCALE);
//               m>=1024 -> out_v[b][m-1024][n'] bf16, n' k-PERMUTED within
//               each 64-col group (k = (j&0x23)|((j&0x0C)<<1)|((j&0x10)>>2))
//               so attn PV A-frags are single ds_read_b128.
// MODE 1 (proj): out_f[b][m][n] fp32 = acc + bias + resid.
template <int MODE>
__global__ __launch_bounds__(256) void gemm_mfma(
    const u16* __restrict__ W, const u16* __restrict__ X,
    const float* __restrict__ bias, const float* __restrict__ resid,
    u16* __restrict__ out_qk, u16* __restrict__ out_v,
    float* __restrict__ out_f)
{
  __shared__ u16 smem[24576];      // 3 x 16KB stage buffers; epilogue overlays
  int id = blockIdx.x;
  int b, xb_, m0, n0;
  if (MODE == 0) {                 // panel-complete halves (see header)
    int half = (id >= 768) ? 1 : 0;
    int r = id - half * 768;
    int y = r >> 6;
    int rr = r & 63;
    b   = rr >> 2;
    xb_ = half * 4 + (rr & 3);
    m0 = y * 128;
    n0 = xb_ * 128;
  } else {
    int yb = id >> 7, rr = id & 127;
    b = rr >> 3; xb_ = rr & 7;
    m0 = yb * 128; n0 = xb_ * 128;
  }
  int t = threadIdx.x, lane = t & 63, w = t >> 6;
  int c = lane & 15, q = lane >> 4;
  int wm = w >> 1, wn = w & 1;
  const u16* Xb = X + (size_t)b * NSP * C_;

  floatx4 acc[4][4];
#pragma unroll
  for (int mi = 0; mi < 4; ++mi)
#pragma unroll
    for (int ni = 0; ni < 4; ++ni) acc[mi][ni] = (floatx4){0.f, 0.f, 0.f, 0.f};

  auto stage = [&](int buf, int k0) {
    u16* Asb = smem + buf * 8192;
    u16* Bsb = Asb + 4096;
#pragma unroll
    for (int it = 0; it < 2; ++it) {
      int task = it * 256 + t;
      int mr = task >> 2;
      int gk = (task & 3) ^ ((mr >> 1) & 3);
      gld16(W + (size_t)(m0 + mr) * C_ + k0 + gk * 8, Asb + task * 8);
    }
#pragma unroll
    for (int it = 0; it < 2; ++it) {
      int task = it * 256 + t;
      int nr = task >> 2;
      int gk = (task & 3) ^ ((nr >> 1) & 3);
      gld16(Xb + (size_t)(n0 + nr) * C_ + k0 + gk * 8, Bsb + task * 8);
    }
  };

  auto compute = [&](int buf) {
    const u16* As = smem + buf * 8192;
    const u16* Bs = As + 4096;
    short8 af[4], bfr[4];
    // group 1: af0, af1, bfr0, bfr1  (issue order = retire order for DS)
#pragma unroll
    for (int mi = 0; mi < 2; ++mi) {
      int m = wm * 64 + mi * 16 + c;
      af[mi] = lds_read_b128(As + m * 32 + ((q ^ ((m >> 1) & 3)) << 3));
    }
#pragma unroll
    for (int ni = 0; ni < 2; ++ni) {
      int n = wn * 64 + ni * 16 + c;
      bfr[ni] = lds_read_b128(Bs + n * 32 + ((q ^ ((n >> 1) & 3)) << 3));
    }
    // group 2: af2, af3, bfr2, bfr3
#pragma unroll
    for (int mi = 2; mi < 4; ++mi) {
      int m = wm * 64 + mi * 16 + c;
      af[mi] = lds_read_b128(As + m * 32 + ((q ^ ((m >> 1) & 3)) << 3));
    }
#pragma unroll
    for (int ni = 2; ni < 4; ++ni) {
      int n = wn * 64 + ni * 16 + c;
      bfr[ni] = lds_read_b128(Bs + n * 32 + ((q ^ ((n >> 1) & 3)) << 3));
    }
    // group 1 landed (4 newest outstanding = group 2)
    asm volatile("s_waitcnt lgkmcnt(4)" ::: "memory");
    __builtin_amdgcn_sched_barrier(0);
    __builtin_amdgcn_s_setprio(1);
#pragma unroll
    for (int mi = 0; mi < 2; ++mi)
#pragma unroll
      for (int ni = 0; ni < 2; ++ni)
        acc[mi][ni] = __builtin_amdgcn_mfma_f32_16x16x32_bf16(
            af[mi], bfr[ni], acc[mi][ni], 0, 0, 0);
    __builtin_amdgcn_s_setprio(0);
    asm volatile("s_waitcnt lgkmcnt(0)" ::: "memory");
    __builtin_amdgcn_sched_barrier(0);
    __builtin_amdgcn_s_setprio(1);
#pragma unroll
    for (int mi = 0; mi < 4; ++mi)
#pragma unroll
      for (int ni = 0; ni < 4; ++ni)
        if (mi >= 2 || ni >= 2)
          acc[mi][ni] = __builtin_amdgcn_mfma_f32_16x16x32_bf16(
              af[mi], bfr[ni], acc[mi][ni], 0, 0, 0);
    __builtin_amdgcn_s_setprio(0);
  };

  stage(0, 0);
  stage(1, 32);
  int cur = 0, tgt = 2;
  for (int ki = 0; ki < 14; ++ki) {
    asm volatile("s_waitcnt vmcnt(4)" ::: "memory");
    __builtin_amdgcn_s_barrier();
    stage(tgt, (ki + 2) * 32);
    compute(cur);
    cur = (cur == 2) ? 0 : cur + 1;
    tgt = (tgt == 2) ? 0 : tgt + 1;
  }
  asm volatile("s_waitcnt vmcnt(4)" ::: "memory");
  __builtin_amdgcn_s_barrier();
  compute(2);                      // ki=14 -> buf 14%3 = 2
  asm volatile("s_waitcnt vmcnt(0)" ::: "memory");
  __builtin_amdgcn_s_barrier();
  compute(0);                      // ki=15 -> buf 15%3 = 0
  __syncthreads();                 // all waves out of buf0 before Cl overlay

  if (MODE == 0) {
    if (m0 < 1024) {       // Q/K region: transpose to [n][m] via LDS
      float sc = (m0 < 512) ? QSCALE : 1.0f;
      u16* Cl = smem;      // [128 n][136 m-stride]
#pragma unroll
      for (int mi = 0; mi < 4; ++mi) {
        floatx4 bi = *(const floatx4*)(bias + m0 + wm * 64 + mi * 16 + q * 4);
#pragma unroll
        for (int ni = 0; ni < 4; ++ni) {
          int n = wn * 64 + ni * 16 + c;
          int m = wm * 64 + mi * 16 + q * 4;
          v4u16 pk;
#pragma unroll
          for (int r = 0; r < 4; ++r) pk[r] = f2bf((acc[mi][ni][r] + bi[r]) * sc);
          *(v4u16*)(Cl + n * 136 + m) = pk;
        }
      }
      __syncthreads();
#pragma unroll
      for (int it = 0; it < 8; ++it) {
        int task = it * 256 + t;
        int n = task >> 4, seg = task & 15;
        v8u16 v = *(const v8u16*)(Cl + n * 136 + seg * 8);
        *(v8u16*)(out_qk + ((size_t)b * NSP + n0 + n) * 1024 + m0 + seg * 8) = v;
      }
    } else {               // V region: [m][n'] via LDS transpose, k-permuted
      u16* Cl = smem;      // [128 m][136 n-stride]
#pragma unroll
      for (int mi = 0; mi < 4; ++mi) {
        floatx4 bi = *(const floatx4*)(bias + m0 + wm * 64 + mi * 16 + q * 4);
#pragma unroll
        for (int ni = 0; ni < 4; ++ni) {
          int n = wn * 64 + ni * 16 + c;
          int m = wm * 64 + mi * 16 + q * 4;
#pragma unroll
          for (int r = 0; r < 4; ++r)
            Cl[(m + r) * 136 + n] = f2bf(acc[mi][ni][r] + bi[r]);
        }
      }
      __syncthreads();
      // store with per-64-group column permutation j -> k:
      // k = (j&0x23) | ((j&0x0C)<<1) | ((j&0x10)>>2).
      // source octet seg*8..+7 maps to two 4-runs at k0 and k0+8,
      // k0 = ((s&4)<<3) | ((s&1)<<4) | ((s&2)<<1), s = seg&7.
#pragma unroll
      for (int it = 0; it < 8; ++it) {
        int task = it * 256 + t;
        int m = task >> 4, seg = task & 15;
        int g64 = seg >> 3, s = seg & 7;
        int k0 = ((s & 4) << 3) | ((s & 1) << 4) | ((s & 2) << 1);
        v8u16 v = *(const v8u16*)(Cl + m * 136 + seg * 8);
        v4u16 lo = { v[0], v[1], v[2], v[3] };
        v4u16 hi = { v[4], v[5], v[6], v[7] };
        size_t base = ((size_t)b * C_ + m0 - 1024 + m) * NSP + n0 + g64 * 64;
        *(v4u16*)(out_v + base + k0) = lo;
        *(v4u16*)(out_v + base + k0 + 8) = hi;
      }
    }
  } else {                 // proj: fp32 [m][n] + bias + residual
#pragma unroll
    for (int mi = 0; mi < 4; ++mi) {
      floatx4 bi = *(const floatx4*)(bias + m0 + wm * 64 + mi * 16 + q * 4);
#pragma unroll
      for (int ni = 0; ni < 4; ++ni) {
        int n = n0 + wn * 64 + ni * 16 + c;
        int m = m0 + wm * 64 + mi * 16 + q * 4;
#pragma unroll
        for (int r = 0; r < 4; ++r) {
          size_t o = ((size_t)b * C_ + m + r) * NSP + n;
          out_f[o] = acc[mi][ni][r] + bi[r] + resid[o];
        }
      }
    }
  }
}

// ---- flash attention v10b (R13, validated) ----
// 4 waves x 32 q-rows; jt2-interleaved QK/exp/PV; asm ds_read frags;
// denominator via mfma(ones,P); V k-permuted; s_setprio around PV.
// Loop protocol: issue prefetch -> vmcnt(4) (previous iter's loads only;
// this iter's 4 stay in flight across the barrier) -> compute -> raw
// s_barrier. Tail j0=15: vmcnt(0).
// Split lgkm wait: lgkmcnt(4) (K landed, V in flight) before QK/exp/pack;
// lgkmcnt(0) only before PV — V-read latency hides under the exp chain.
__global__ __launch_bounds__(256, 4) void attn_mfma(
    const u16* __restrict__ qk, const u16* __restrict__ vbuf,
    u16* __restrict__ att)
{
  __shared__ u16 __align__(16) smem[16384];   // 32 KB
  int id = blockIdx.x;
  int hb = id & 127;
  int i0 = id >> 7;
  int h = hb >> 4, b = hb & 15;
  int t = threadIdx.x, lane = t & 63, w = t >> 6;
  int c = lane & 15, q = lane >> 4;
  const u16* qbase = qk + (size_t)b * NSP * 1024;
  const u16* vbase = vbuf + (size_t)(b * C_ + h * 64) * NSP;

  // stage Q(128x64) -> [0..8192); K0 -> [8192..12288); V0 -> [12288..16384)
#pragma unroll
  for (int it = 0; it < 4; ++it) {
    int task = it * 256 + t;
    int r = task >> 3, seg = task & 7, ds = (seg ^ (r & 7)) * 8;
    gld16(qbase + (size_t)(i0 * 128 + r) * 1024 + h * 64 + ds, smem + task * 8);
  }
#pragma unroll
  for (int it = 0; it < 2; ++it) {
    int task = it * 256 + t;
    int r = task >> 3, seg = task & 7, ds = (seg ^ (r & 7)) * 8;
    gld16(qbase + (size_t)r * 1024 + 512 + h * 64 + ds, smem + 8192 + task * 8);
    gld16(vbase + (size_t)r * NSP + ds, smem + 12288 + task * 8);
  }
  __syncthreads();

  short8 qa[2][2];                 // rows w*32 + nf*16 + c
#pragma unroll
  for (int nf = 0; nf < 2; ++nf) {
    int row = w * 32 + nf * 16 + c;
#pragma unroll
    for (int ch = 0; ch < 2; ++ch)
      qa[nf][ch] = *(const short8*)(smem + row * 64 + (((q + 4 * ch) ^ (c & 7)) << 3));
  }
  __syncthreads();                 // all waves done reading Q before overlay

  short8 onesf;                    // all-ones bf16 A-operand (1.0 = 0x3F80)
#pragma unroll
  for (int u = 0; u < 8; ++u) onesf[u] = (short)0x3F80;

  floatx4 Oacc[4][2];              // [dt][nf]
  floatx4 OaccT[2];                // ones-MFMA column sums -> denominator
#pragma unroll
  for (int dt = 0; dt < 4; ++dt)
#pragma unroll
    for (int nf = 0; nf < 2; ++nf) Oacc[dt][nf] = (floatx4){0.f, 0.f, 0.f, 0.f};
#pragma unroll
  for (int nf = 0; nf < 2; ++nf) OaccT[nf] = (floatx4){0.f, 0.f, 0.f, 0.f};

  for (int j0 = 0; j0 < 16; ++j0) {
    int p = j0 & 1;
    u16* KS = smem + (p ? 0 : 8192);
    u16* VS = KS + 4096;
    if (j0 < 15) {                 // prefetch next K/V into the other parity
      u16* KN = smem + (p ? 8192 : 0);
      u16* VN = KN + 4096;
#pragma unroll
      for (int it = 0; it < 2; ++it) {
        int task = it * 256 + t;
        int r = task >> 3, seg = task & 7, ds = (seg ^ (r & 7)) * 8;
        gld16(qbase + (size_t)((j0 + 1) * 64 + r) * 1024 + 512 + h * 64 + ds,
              KN + task * 8);
        gld16(vbase + (size_t)r * NSP + (j0 + 1) * 64 + ds, VN + task * 8);
      }
      asm volatile("s_waitcnt vmcnt(4)" ::: "memory");
    } else {
      asm volatile("s_waitcnt vmcnt(0)" ::: "memory");   // tail: drain last
    }
    __builtin_amdgcn_sched_barrier(0);
#pragma unroll
    for (int jt2 = 0; jt2 < 2; ++jt2) {
      // --- asm frag reads: 4x K then 4x V (issue order = retire order) ---
      short8 kb[2][2], vf[4];
#pragma unroll
      for (int jj = 0; jj < 2; ++jj) {
        int row = (jt2 * 2 + jj) * 16 + c;
        kb[jj][0] = lds_read_b128(KS + row * 64 + ((q ^ (row & 7)) << 3));
        kb[jj][1] = lds_read_b128(KS + row * 64 + (((q + 4) ^ (row & 7)) << 3));
      }
#pragma unroll
      for (int dt = 0; dt < 4; ++dt) {
        int dd = dt * 16 + c;
        vf[dt] = lds_read_b128(VS + dd * 64 + (((jt2 * 4 + q) ^ (dd & 7)) << 3));
      }
      // split wait: K landed (V's 4 reads still in flight)
      asm volatile("s_waitcnt lgkmcnt(4)" ::: "memory");
      __builtin_amdgcn_sched_barrier(0);
      // --- QK half: S^T = K·Q^T for 32 j, base-2 exp, pack P bf16 ---
      //     (V reads land underneath this exp chain)
      unsigned pk2[2][2][2];
#pragma unroll
      for (int jj = 0; jj < 2; ++jj) {
#pragma unroll
        for (int nf = 0; nf < 2; ++nf) {
          floatx4 z = (floatx4){0.f, 0.f, 0.f, 0.f};
          z = __builtin_amdgcn_mfma_f32_16x16x32_bf16(kb[jj][0], qa[nf][0], z, 0, 0, 0);
          z = __builtin_amdgcn_mfma_f32_16x16x32_bf16(kb[jj][1], qa[nf][1], z, 0, 0, 0);
          float p0 = __builtin_amdgcn_exp2f(z[0]);
          float p1 = __builtin_amdgcn_exp2f(z[1]);
          float p2 = __builtin_amdgcn_exp2f(z[2]);
          float p3 = __builtin_amdgcn_exp2f(z[3]);
          pk2[jj][nf][0] = pk_bf(p0, p1);
          pk2[jj][nf][1] = pk_bf(p2, p3);
        }
      }
      short8 pf[2];
#pragma unroll
      for (int nf = 0; nf < 2; ++nf) {
        union { short8 s; unsigned d[4]; } u;
        u.d[0] = pk2[0][nf][0]; u.d[1] = pk2[0][nf][1];
        u.d[2] = pk2[1][nf][0]; u.d[3] = pk2[1][nf][1];
        pf[nf] = u.s;
      }
      // --- PV half: wait V reads, then k-permuted V MFMAs ---
      asm volatile("s_waitcnt lgkmcnt(0)" ::: "memory");
      __builtin_amdgcn_sched_barrier(0);
      __builtin_amdgcn_s_setprio(1);
#pragma unroll
      for (int dt = 0; dt < 4; ++dt)
#pragma unroll
        for (int nf = 0; nf < 2; ++nf)
          Oacc[dt][nf] = __builtin_amdgcn_mfma_f32_16x16x32_bf16(
              vf[dt], pf[nf], Oacc[dt][nf], 0, 0, 0);
#pragma unroll
      for (int nf = 0; nf < 2; ++nf)
        OaccT[nf] = __builtin_amdgcn_mfma_f32_16x16x32_bf16(
            onesf, pf[nf], OaccT[nf], 0, 0, 0);
      __builtin_amdgcn_s_setprio(0);
    }
    __builtin_amdgcn_s_barrier();  // raw barrier: NO vmcnt drain (T4)
  }

  // ---- epilogue: denominator straight from ones-MFMA rows (all equal) ----
#pragma unroll
  for (int nf = 0; nf < 2; ++nf) {
    float rinv = 1.f / OaccT[nf][0];
    int n = i0 * 128 + w * 32 + nf * 16 + c;
#pragma unroll
    for (int dt = 0; dt < 4; ++dt) {
      v4u16 pk;
#pragma unroll
      for (int r = 0; r < 4; ++r) pk[r] = f2bf(Oacc[dt][nf][r] * rinv);
      *(v4u16*)(att + ((size_t)b * NSP + n) * C_ + h * 64 + dt * 16 + q * 4) = pk;
    }
  }
}

extern "C" void kernel_launch(void* const* d_in, const int* in_sizes, int n_in,
                              void* d_out, int out_size, void* d_ws, size_t ws_size,
                              hipStream_t stream)
{
  const float* x    = (const float*)d_in[0];
  const float* gw   = (const float*)d_in[1];
  const float* gb   = (const float*)d_in[2];
  const float* qkvw = (const float*)d_in[3];
  const float* qkvb = (const float*)d_in[4];
  const float* pw   = (const float*)d_in[5];
  const float* pb   = (const float*)d_in[6];
  float* out = (float*)d_out;

  u16* xn    = (u16*)d_ws;             // [b][n][c]
  u16* qkb   = xn   + 8388608;         // [b][n][1024]
  u16* vbf   = qkb  + 16777216;        // [b][dd][n'] (k-permuted 64-groups)
  u16* attb  = vbf  + 8388608;         // [b][n][c]
  u16* wq    = attb + 8388608;         // [1536][512]
  u16* wp    = wq   + 786432;          // [512][512]
  float* stats = (float*)(wp + 262144);  // [128][2] fp32

  hipMemsetAsync(stats, 0, 128 * 2 * sizeof(float), stream);
  gn_stats_cvt<<<2048, 256, 0, stream>>>(x, stats, qkvw, wq, pw, wp);
  gn_apply<<<2048, 256, 0, stream>>>(x, stats, gw, gb, xn);
  gemm_mfma<0><<<dim3(1536), 256, 0, stream>>>(
      wq, xn, qkvb, nullptr, qkb, vbf, nullptr);
  attn_mfma<<<dim3(1024), 256, 0, stream>>>(qkb, vbf, attb);
  gemm_mfma<1><<<dim3(512), 256, 0, stream>>>(
      wp, attb, pb, x, nullptr, nullptr, out);
}